// Round 4
// baseline (546.847 us; speedup 1.0000x reference)
//
#include <hip/hip_runtime.h>
#include <cstddef>

typedef float f32x4 __attribute__((ext_vector_type(4)));
typedef __bf16 bf16x8 __attribute__((ext_vector_type(8)));
typedef unsigned short u16x8 __attribute__((ext_vector_type(8)));
typedef unsigned short u16x4 __attribute__((ext_vector_type(4)));

constexpr int NB = 2, S = 4096, H = 16, D = 128;
constexpr int DIN = 2048, NQKV = 6144, HD = 2048;
constexpr int BLK = 256, NBL = 16;

constexpr size_t SZ_XB    = (size_t)NB * S * DIN * 2;
constexpr size_t SZ_WQKVT = (size_t)NQKV * DIN * 2;
constexpr size_t SZ_WGT   = (size_t)HD * DIN * 2;
constexpr size_t SZ_WOUTT = (size_t)HD * HD * 2;
constexpr size_t SZ_QKVB  = (size_t)NB * S * NQKV * 2;
constexpr size_t SZ_GB    = (size_t)NB * S * HD * 2;
constexpr size_t SZ_ST    = (size_t)NB * H * NBL * D * D * 2;
constexpr size_t SZ_OB    = (size_t)NB * S * HD * 2;

__device__ __forceinline__ float bf2f(unsigned short u) {
  return __uint_as_float(((unsigned)u) << 16);
}
__device__ __forceinline__ unsigned short f2bf(float f) {
  unsigned u = __float_as_uint(f);
  u += 0x7fffu + ((u >> 16) & 1u);
  return (unsigned short)(u >> 16);
}
__device__ __forceinline__ void gload16(const void* g, void* l) {
  __builtin_amdgcn_global_load_lds(
      (const __attribute__((address_space(1))) unsigned int*)g,
      (__attribute__((address_space(3))) unsigned int*)l, 16, 0, 0);
}

// ---------------- fp32 -> bf16 elementwise convert (8 elems/thread) --------
__global__ __launch_bounds__(256) void cvt_bf16(
    const float* __restrict__ in, unsigned short* __restrict__ out) {
  const size_t id = (size_t)blockIdx.x * 256 + threadIdx.x;
  const float4 a = *(const float4*)&in[id * 8];
  const float4 c = *(const float4*)&in[id * 8 + 4];
  u16x8 o;
  o[0] = f2bf(a.x); o[1] = f2bf(a.y); o[2] = f2bf(a.z); o[3] = f2bf(a.w);
  o[4] = f2bf(c.x); o[5] = f2bf(c.y); o[6] = f2bf(c.z); o[7] = f2bf(c.w);
  *(u16x8*)&out[id * 8] = o;
}

// ---------------- W[K][N] f32  ->  Wt[N][K] bf16 (32x32 LDS tiles) ---------
__global__ __launch_bounds__(256) void transpose_cvt(
    const float* __restrict__ W, unsigned short* __restrict__ Wt, int K, int N) {
  __shared__ unsigned short tile[32][33];
  const int n0 = blockIdx.x * 32, k0 = blockIdx.y * 32;
  const int t = threadIdx.x;
  const int r = t >> 3, c4 = (t & 7) * 4;
  const float4 v = *(const float4*)&W[(size_t)(k0 + r) * N + n0 + c4];
  tile[r][c4 + 0] = f2bf(v.x);
  tile[r][c4 + 1] = f2bf(v.y);
  tile[r][c4 + 2] = f2bf(v.z);
  tile[r][c4 + 3] = f2bf(v.w);
  __syncthreads();
  u16x4 o;
  #pragma unroll
  for (int i = 0; i < 4; ++i) o[i] = tile[c4 + i][r];
  *(u16x4*)&Wt[(size_t)(n0 + r) * K + k0 + c4] = o;
}

// ---------------- 256^2 phased-pipeline bf16 MFMA GEMM: C = act(A @ Bt^T) --
// A [M][K], Bt [N][K] bf16 row-major. 512 thr = 8 waves (2Mx4N), 128x64/wave.
// K in 32-wide tiles; 4-slot LDS ring (A 16K + B 16K per slot), staged 3 ahead
// via global_load_lds; per tile TWO phases, each {ds_read || 2 gloads -> BAR
// -> setprio MFMA x16 -> BAR}; counted vmcnt(8) once per tile (never 0).
// LDS swizzle (64B rows): byte(row,cg) = row*64 + ((cg*16) ^ ((row&3)<<4));
// staging keeps LDS linear, global SOURCE pre-swizzled (involution).
// ACT: 0 none->f32, 1 silu->bf16, 2 sigmoid->bf16.
template<int ACT>
__global__ __launch_bounds__(512, 2) void gemm256(
    const unsigned short* __restrict__ A, const unsigned short* __restrict__ Bt,
    void* __restrict__ C, int M, int N, int K) {
  __shared__ unsigned short lds[65536];          // 128 KiB = 4 slots x 32 KiB
  char* ldsb = (char*)lds;
  const int t = threadIdx.x;
  const int lane = t & 63, wave = t >> 6;
  const int wr = wave >> 2, wc = wave & 3;       // 2 x 4 wave grid

  // XCD-patched block swizzle: XCD x owns bm-stripe [x*nbm/8, ...), bn-major
  // inside -> 32 concurrent blocks/XCD = 4bm x 8bn patch (L2 reuse A x8, B x4)
  const int nbm = M >> 8, nbn = N >> 8;
  const int nbmx = nbm >> 3;                     // nbm/8 (all our M: 32 -> 4)
  const int xcd = blockIdx.x & 7, q = blockIdx.x >> 3;
  const int bm = xcd * nbmx + (q % nbmx);
  const int bn = q / nbmx;

  // ---- staging source (swizzle-decoded): lane l covers row l>>2, colgrp
  // (l&3)^((l>>2)&3)  [decode of byte(row,cg) above at linear dst l*16]
  const int lrow = lane >> 2;
  const int lcg  = (lane & 3) ^ (lrow & 3);
  const unsigned short* sA0 = A  + (size_t)(bm * 256 + wave * 32 + lrow) * K + lcg * 8;
  const unsigned short* sA1 = A  + (size_t)(bm * 256 + wave * 32 + 16 + lrow) * K + lcg * 8;
  const unsigned short* sB0 = Bt + (size_t)(bn * 256 + wave * 32 + lrow) * K + lcg * 8;
  const unsigned short* sB1 = Bt + (size_t)(bn * 256 + wave * 32 + 16 + lrow) * K + lcg * 8;
  const int dA0 = wave * 2048, dA1 = wave * 2048 + 1024;
  const int dB0 = 16384 + dA0, dB1 = 16384 + dA1;

  // ---- ds_read fragment offsets (swizzled) ----
  const int cgb = (lane >> 4) << 4;              // col-group byte 0/16/32/48
  int offA[8], offB[4];
  #pragma unroll
  for (int m = 0; m < 8; ++m) {
    const int row = wr * 128 + m * 16 + (lane & 15);
    offA[m] = row * 64 + (cgb ^ ((row & 3) << 4));
  }
  #pragma unroll
  for (int n = 0; n < 4; ++n) {
    const int row = wc * 64 + n * 16 + (lane & 15);
    offB[n] = 16384 + row * 64 + (cgb ^ ((row & 3) << 4));
  }

  const int NT = K >> 5;                         // 32-wide K tiles (2048 -> 64)
  #define STG_A(u) { const int _s = ((u) & 3) * 32768; const int _o = (u) * 32; \
    gload16(sA0 + _o, ldsb + _s + dA0); gload16(sA1 + _o, ldsb + _s + dA1); }
  #define STG_B(u) { const int _s = ((u) & 3) * 32768; const int _o = (u) * 32; \
    gload16(sB0 + _o, ldsb + _s + dB0); gload16(sB1 + _o, ldsb + _s + dB1); }

  STG_A(0); STG_B(0); STG_A(1); STG_B(1); STG_A(2); STG_B(2);
  asm volatile("s_waitcnt vmcnt(8)" ::: "memory");   // tile 0 landed
  __builtin_amdgcn_s_barrier();

  f32x4 acc[8][4] = {};
  for (int u = 0; u < NT; ++u) {
    const int slot = (u & 3) * 32768;
    bf16x8 af[4], bf[4];
    // ---- phase 0: ds-issue (B all + A lower half) || stage A(u+3) ----
    #pragma unroll
    for (int n = 0; n < 4; ++n) bf[n] = *(const bf16x8*)(ldsb + slot + offB[n]);
    #pragma unroll
    for (int m = 0; m < 4; ++m) af[m] = *(const bf16x8*)(ldsb + slot + offA[m]);
    if (u + 3 < NT) STG_A(u + 3);                // slot((u-1)&3): freed at u-1's
    __builtin_amdgcn_s_barrier();                //   trailing barrier
    __builtin_amdgcn_s_setprio(1);
    #pragma unroll
    for (int m = 0; m < 4; ++m)
      #pragma unroll
      for (int n = 0; n < 4; ++n)
        acc[m][n] = __builtin_amdgcn_mfma_f32_16x16x32_bf16(af[m], bf[n], acc[m][n], 0, 0, 0);
    __builtin_amdgcn_s_setprio(0);
    __builtin_amdgcn_s_barrier();
    // ---- phase 1: ds-issue (A upper half) || stage B(u+3); counted vmcnt ----
    #pragma unroll
    for (int m = 0; m < 4; ++m) af[m] = *(const bf16x8*)(ldsb + slot + offA[4 + m]);
    if (u + 3 < NT) STG_B(u + 3);
    if (u < NT - 3)       asm volatile("s_waitcnt vmcnt(8)" ::: "memory");  // u+1 landed
    else if (u == NT - 3) asm volatile("s_waitcnt vmcnt(4)" ::: "memory");
    else                  asm volatile("s_waitcnt vmcnt(0)" ::: "memory");
    __builtin_amdgcn_s_barrier();
    __builtin_amdgcn_s_setprio(1);
    #pragma unroll
    for (int m = 0; m < 4; ++m)
      #pragma unroll
      for (int n = 0; n < 4; ++n)
        acc[4 + m][n] = __builtin_amdgcn_mfma_f32_16x16x32_bf16(af[m], bf[n], acc[4 + m][n], 0, 0, 0);
    __builtin_amdgcn_s_setprio(0);
    __builtin_amdgcn_s_barrier();
  }
  #undef STG_A
  #undef STG_B

  // epilogue: C/D layout col = lane&15, row = (lane>>4)*4 + reg  [m89-verified]
  const int ro = (lane >> 4) * 4, co = lane & 15;
  #pragma unroll
  for (int m = 0; m < 8; ++m)
    #pragma unroll
    for (int n = 0; n < 4; ++n) {
      const int gc = bn * 256 + wc * 64 + n * 16 + co;
      #pragma unroll
      for (int r = 0; r < 4; ++r) {
        const int gr = bm * 256 + wr * 128 + m * 16 + ro + r;
        float v = acc[m][n][r];
        if constexpr (ACT == 1) v = v / (1.f + __expf(-v));     // silu
        if constexpr (ACT == 2) v = 1.f / (1.f + __expf(-v));   // sigmoid
        if constexpr (ACT == 0) ((float*)C)[(size_t)gr * N + gc] = v;
        else ((unsigned short*)C)[(size_t)gr * N + gc] = f2bf(v);
      }
    }
}

// ---------------- per-block KV outer product, TRANSPOSED out ---------------
// st[(bh*NBL+j)][f][e] = sum_m (k[m][e]*kdecay[m]) * v[m][f]   (bf16)
__global__ __launch_bounds__(256) void kv_outer(
    const unsigned short* __restrict__ qkv, unsigned short* __restrict__ st) {
  const int gid = blockIdx.x;
  const int j = gid & 15;
  const int bh = gid >> 4;
  const int h = bh & 15;
  const int b = bh >> 4;
  const float slope = exp2f(-0.5f * (float)(h + 1));
  const int t = threadIdx.x;
  __shared__ unsigned short kl[64][136];
  __shared__ unsigned short vl[64][136];
  float acc[8][8] = {};
  const int e0 = (t >> 4) * 8, f0 = (t & 15) * 8;
  for (int ch = 0; ch < 4; ++ch) {
    if (ch) __syncthreads();
    #pragma unroll
    for (int i = 0; i < 4; ++i) {
      const int cc = t + 256 * i;
      const int r = cc >> 4, c0 = (cc & 15) * 8;
      const int mb = ch * 64 + r;
      const int seq = b * S + j * BLK + mb;
      const u16x8 k8 = *(const u16x8*)&qkv[(size_t)seq * NQKV + h * 384 + 128 + c0];
      const float kd = expf(-slope * (float)(255 - mb));
      u16x8 kw;
      #pragma unroll
      for (int q2 = 0; q2 < 8; ++q2) kw[q2] = f2bf(bf2f(k8[q2]) * kd);
      *(u16x8*)&kl[r][c0] = kw;
      *(u16x8*)&vl[r][c0] = *(const u16x8*)&qkv[(size_t)seq * NQKV + h * 384 + 256 + c0];
    }
    __syncthreads();
    for (int m = 0; m < 64; ++m) {
      const u16x8 k8 = *(const u16x8*)&kl[m][e0];
      const u16x8 v8 = *(const u16x8*)&vl[m][f0];
      float kf[8], vf[8];
      #pragma unroll
      for (int q2 = 0; q2 < 8; ++q2) { kf[q2] = bf2f(k8[q2]); vf[q2] = bf2f(v8[q2]); }
      #pragma unroll
      for (int i = 0; i < 8; ++i)
        #pragma unroll
        for (int q2 = 0; q2 < 8; ++q2) acc[i][q2] += kf[i] * vf[q2];
    }
  }
  const size_t base = (size_t)gid * (D * D);
  #pragma unroll
  for (int q2 = 0; q2 < 8; ++q2) {           // transposed: st[f][e]
    u16x8 ow;
    #pragma unroll
    for (int i = 0; i < 8; ++i) ow[i] = f2bf(acc[i][q2]);
    *(u16x8*)&st[base + (size_t)(f0 + q2) * D + e0] = ow;
  }
}

// ---------------- exclusive decay scan over blocks (per element) -----------
__global__ __launch_bounds__(256) void kv_scan(unsigned short* __restrict__ st) {
  const int id = blockIdx.x * 256 + threadIdx.x;  // NB*H*D*D threads
  const int ef = id & (D * D - 1);
  const int bh = id >> 14;
  const int h = bh & 15;
  const float slope = exp2f(-0.5f * (float)(h + 1));
  const float bd = expf(-slope * 256.f);
  unsigned short* p = st + (size_t)bh * NBL * D * D + ef;
  float cur = 0.f;
  #pragma unroll
  for (int jj = 0; jj < NBL; ++jj) {
    const float m = bf2f(p[(size_t)jj * D * D]);
    p[(size_t)jj * D * D] = f2bf(cur);
    cur = bd * cur + m;
  }
}

// ---------------- MFMA attention -------------------------------------------
// grid = ((b*H+h)*NBL + j)*2 + half ; WG = 4 waves, 128 q-rows x 128 dims.
// out = qdecay.*(q @ kvT^T) + (mask(q@k^T).*decay) @ v
__global__ __launch_bounds__(256) void attn_mfma(
    const unsigned short* __restrict__ qkv, const unsigned short* __restrict__ st,
    unsigned short* __restrict__ ob) {
  const int gid = blockIdx.x;
  const int half = gid & 1;
  const int rest = gid >> 1;
  const int j = rest & 15;
  const int bh = rest >> 4;
  const int h = bh & 15;
  const int b = bh >> 4;
  const float slope = exp2f(-0.5f * (float)(h + 1));
  const int t = threadIdx.x;
  const int lane = t & 63, wave = t >> 6, wr = wave >> 1, wc = wave & 1;

  __shared__ unsigned short ql[128][136];   // q rows (m x e)
  __shared__ unsigned short cb[128][136];   // kvT / k / vT chunk buffer
  __shared__ unsigned short pl[128][136];   // decayed P (m x m') bf16

  // stage q and kvT (state is pre-transposed [f][e], exclusive-scanned)
  {
    const int r = t >> 4, c0 = (t & 15) * 8;
    const size_t stbase = (size_t)rest * (D * D);
    #pragma unroll
    for (int p = 0; p < 8; ++p) {
      const int seq = b * S + j * BLK + half * 128 + r + p * 16;
      *(u16x8*)&ql[r + p * 16][c0] = *(const u16x8*)&qkv[(size_t)seq * NQKV + h * 384 + c0];
      *(u16x8*)&cb[r + p * 16][c0] = *(const u16x8*)&st[stbase + (size_t)(r + p * 16) * D + c0];
    }
  }
  __syncthreads();

  f32x4 acc[4][4] = {};
  // ---- phase 1: non-diag = q @ kvT^T ----
  #pragma unroll
  for (int kk = 0; kk < 4; ++kk) {
    bf16x8 af[4], bfr[4];
    #pragma unroll
    for (int m = 0; m < 4; ++m)
      af[m] = *(const bf16x8*)&ql[wr * 64 + m * 16 + (lane & 15)][kk * 32 + (lane >> 4) * 8];
    #pragma unroll
    for (int n = 0; n < 4; ++n)
      bfr[n] = *(const bf16x8*)&cb[wc * 64 + n * 16 + (lane & 15)][kk * 32 + (lane >> 4) * 8];
    #pragma unroll
    for (int m = 0; m < 4; ++m)
      #pragma unroll
      for (int n = 0; n < 4; ++n)
        acc[m][n] = __builtin_amdgcn_mfma_f32_16x16x32_bf16(af[m], bfr[n], acc[m][n], 0, 0, 0);
  }
  // apply q_decay = exp(-slope*(gm+1)) to the non-diag part
  const int ro = (lane >> 4) * 4;
  #pragma unroll
  for (int m = 0; m < 4; ++m)
    #pragma unroll
    for (int r = 0; r < 4; ++r) {
      const int gm = half * 128 + wr * 64 + m * 16 + ro + r;
      const float qd = expf(-slope * (float)(gm + 1));
      #pragma unroll
      for (int n = 0; n < 4; ++n) acc[m][n][r] *= qd;
    }

  // ---- phase 2: intra-block causal, chunks of 128 k-rows ----
  const int nch = 1 + half;
  for (int c = 0; c < nch; ++c) {
    __syncthreads();                         // cb free (prev readers done)
    {
      const int r = t >> 4, c0 = (t & 15) * 8;
      #pragma unroll
      for (int p = 0; p < 8; ++p) {
        const int seq = b * S + j * BLK + c * 128 + r + p * 16;
        *(u16x8*)&cb[r + p * 16][c0] = *(const u16x8*)&qkv[(size_t)seq * NQKV + h * 384 + 128 + c0];
      }
    }
    __syncthreads();
    f32x4 sacc[4][4] = {};
    #pragma unroll
    for (int kk = 0; kk < 4; ++kk) {
      bf16x8 af[4], bfr[4];
      #pragma unroll
      for (int m = 0; m < 4; ++m)
        af[m] = *(const bf16x8*)&ql[wr * 64 + m * 16 + (lane & 15)][kk * 32 + (lane >> 4) * 8];
      #pragma unroll
      for (int n = 0; n < 4; ++n)
        bfr[n] = *(const bf16x8*)&cb[wc * 64 + n * 16 + (lane & 15)][kk * 32 + (lane >> 4) * 8];
      #pragma unroll
      for (int m = 0; m < 4; ++m)
        #pragma unroll
        for (int n = 0; n < 4; ++n)
          sacc[m][n] = __builtin_amdgcn_mfma_f32_16x16x32_bf16(af[m], bfr[n], sacc[m][n], 0, 0, 0);
    }
    // decay+mask -> P (bf16) in LDS
    #pragma unroll
    for (int m = 0; m < 4; ++m)
      #pragma unroll
      for (int n = 0; n < 4; ++n) {
        const int lc = wc * 64 + n * 16 + (lane & 15);
        const int gp = c * 128 + lc;
        #pragma unroll
        for (int r = 0; r < 4; ++r) {
          const int lm = wr * 64 + m * 16 + ro + r;
          const int gm = half * 128 + lm;
          const float dd = (gm >= gp) ? expf(-slope * (float)(gm - gp)) : 0.f;
          pl[lm][lc] = f2bf(sacc[m][n][r] * dd);
        }
      }
    __syncthreads();                         // P complete; cb readers done
    // stage v transposed: cb[f][m']
    {
      const int vr = t & 15, vc0 = (t >> 4) * 8;
      #pragma unroll
      for (int p = 0; p < 8; ++p) {
        const int row = vr + p * 16;
        const int seq = b * S + j * BLK + c * 128 + row;
        const u16x8 vv = *(const u16x8*)&qkv[(size_t)seq * NQKV + h * 384 + 256 + vc0];
        #pragma unroll
        for (int i = 0; i < 8; ++i) cb[vc0 + i][row] = vv[i];
      }
    }
    __syncthreads();
    // PV: acc += P @ vT^T
    #pragma unroll
    for (int kk = 0; kk < 4; ++kk) {
      bf16x8 af[4], bfr[4];
      #pragma unroll
      for (int m = 0; m < 4; ++m)
        af[m] = *(const bf16x8*)&pl[wr * 64 + m * 16 + (lane & 15)][kk * 32 + (lane >> 4) * 8];
      #pragma unroll
      for (int n = 0; n < 4; ++n)
        bfr[n] = *(const bf16x8*)&cb[wc * 64 + n * 16 + (lane & 15)][kk * 32 + (lane >> 4) * 8];
      #pragma unroll
      for (int m = 0; m < 4; ++m)
        #pragma unroll
        for (int n = 0; n < 4; ++n)
          acc[m][n] = __builtin_amdgcn_mfma_f32_16x16x32_bf16(af[m], bfr[n], acc[m][n], 0, 0, 0);
    }
  }

  // epilogue: ob[b][n][h*D + f]
  #pragma unroll
  for (int m = 0; m < 4; ++m)
    #pragma unroll
    for (int n = 0; n < 4; ++n) {
      const int fc = h * D + wc * 64 + n * 16 + (lane & 15);
      #pragma unroll
      for (int r = 0; r < 4; ++r) {
        const int seq = b * S + j * BLK + half * 128 + wr * 64 + m * 16 + ro + r;
        ob[(size_t)seq * HD + fc] = f2bf(acc[m][n][r]);
      }
    }
}

// ---------------- RMSNorm * norm_w * sigmoid-gate -> bf16 ------------------
__global__ __launch_bounds__(256) void norm_gate(
    const unsigned short* __restrict__ ob, const unsigned short* __restrict__ gb,
    const float* __restrict__ nw, unsigned short* __restrict__ og) {
  const int row = blockIdx.x;
  const int t = threadIdx.x;
  const u16x8 ov = *(const u16x8*)&ob[(size_t)row * HD + t * 8];
  float f[8];
  float ss = 0.f;
  #pragma unroll
  for (int i = 0; i < 8; ++i) { f[i] = bf2f(ov[i]); ss += f[i] * f[i]; }
  #pragma unroll
  for (int off = 32; off > 0; off >>= 1) ss += __shfl_down(ss, off, 64);
  __shared__ float red[4];
  if ((t & 63) == 0) red[t >> 6] = ss;
  __syncthreads();
  const float rms = rsqrtf((red[0] + red[1] + red[2] + red[3]) * (1.f / HD) + 1e-6f);
  const u16x8 gv = *(const u16x8*)&gb[(size_t)row * HD + t * 8];
  u16x8 ow;
  #pragma unroll
  for (int i = 0; i < 8; ++i)
    ow[i] = f2bf(f[i] * rms * nw[t * 8 + i] * bf2f(gv[i]));
  *(u16x8*)&og[(size_t)row * HD + t * 8] = ow;
}

extern "C" void kernel_launch(void* const* d_in, const int* in_sizes, int n_in,
                              void* d_out, int out_size, void* d_ws, size_t ws_size,
                              hipStream_t stream) {
  (void)in_sizes; (void)n_in; (void)out_size; (void)ws_size;
  const float* x    = (const float*)d_in[0];
  const float* Wqkv = (const float*)d_in[1];
  const float* Wg   = (const float*)d_in[2];
  const float* Wout = (const float*)d_in[3];
  const float* nw   = (const float*)d_in[4];

  char* ws = (char*)d_ws;
  unsigned short* xb    = (unsigned short*)ws; ws += SZ_XB;
  unsigned short* wqkvt = (unsigned short*)ws; ws += SZ_WQKVT;
  unsigned short* wgt   = (unsigned short*)ws; ws += SZ_WGT;
  unsigned short* woutt = (unsigned short*)ws; ws += SZ_WOUTT;
  unsigned short* qkvb  = (unsigned short*)ws; ws += SZ_QKVB;
  unsigned short* gb    = (unsigned short*)ws; ws += SZ_GB;
  unsigned short* st    = (unsigned short*)ws; ws += SZ_ST;
  unsigned short* ob    = (unsigned short*)ws; ws += SZ_OB;
  unsigned short* og    = xb;  // alias: xb dead after the gate GEMM

  cvt_bf16<<<dim3((NB * S * DIN) / (256 * 8)), 256, 0, stream>>>(x, xb);
  transpose_cvt<<<dim3(NQKV / 32, DIN / 32), 256, 0, stream>>>(Wqkv, wqkvt, DIN, NQKV);
  transpose_cvt<<<dim3(HD / 32, DIN / 32), 256, 0, stream>>>(Wg, wgt, DIN, HD);
  transpose_cvt<<<dim3(HD / 32, HD / 32), 256, 0, stream>>>(Wout, woutt, HD, HD);

  // qkv = silu(x @ Wqkv), gate = sigmoid(x @ Wg)
  gemm256<1><<<dim3((NB * S / 256) * (NQKV / 256)), 512, 0, stream>>>(xb, wqkvt, qkvb, NB * S, NQKV, DIN);
  gemm256<2><<<dim3((NB * S / 256) * (HD / 256)), 512, 0, stream>>>(xb, wgt, gb, NB * S, HD, DIN);

  kv_outer<<<dim3(NB * H * NBL), 256, 0, stream>>>(qkvb, st);
  kv_scan<<<dim3((NB * H * D * D) / 256), 256, 0, stream>>>(st);
  attn_mfma<<<dim3(NB * H * NBL * 2), 256, 0, stream>>>(qkvb, st, ob);

  norm_gate<<<dim3(NB * S), 256, 0, stream>>>(ob, gb, nw, og);
  gemm256<0><<<dim3((NB * S / 256) * (HD / 256)), 512, 0, stream>>>(og, woutt, d_out, NB * S, HD, HD);
}

// Round 5
// 531.123 us; speedup vs baseline: 1.0296x; 1.0296x over previous
//
#include <hip/hip_runtime.h>
#include <cstddef>

typedef float f32x4 __attribute__((ext_vector_type(4)));
typedef __bf16 bf16x8 __attribute__((ext_vector_type(8)));
typedef unsigned short u16x8 __attribute__((ext_vector_type(8)));
typedef unsigned short u16x4 __attribute__((ext_vector_type(4)));

constexpr int NB = 2, S = 4096, H = 16, D = 128;
constexpr int DIN = 2048, NQKV = 6144, HD = 2048;
constexpr int BLK = 256, NBL = 16;

constexpr size_t SZ_XB    = (size_t)NB * S * DIN * 2;
constexpr size_t SZ_WQKVT = (size_t)NQKV * DIN * 2;
constexpr size_t SZ_WGT   = (size_t)HD * DIN * 2;
constexpr size_t SZ_WOUTT = (size_t)HD * HD * 2;
constexpr size_t SZ_QKVB  = (size_t)NB * S * NQKV * 2;
constexpr size_t SZ_GB    = (size_t)NB * S * HD * 2;
constexpr size_t SZ_ST    = (size_t)NB * H * NBL * D * D * 2;
constexpr size_t SZ_OB    = (size_t)NB * S * HD * 2;

__device__ __forceinline__ float bf2f(unsigned short u) {
  return __uint_as_float(((unsigned)u) << 16);
}
__device__ __forceinline__ unsigned short f2bf(float f) {
  unsigned u = __float_as_uint(f);
  u += 0x7fffu + ((u >> 16) & 1u);
  return (unsigned short)(u >> 16);
}
__device__ __forceinline__ void gload16(const void* g, void* l) {
  __builtin_amdgcn_global_load_lds(
      (const __attribute__((address_space(1))) unsigned int*)g,
      (__attribute__((address_space(3))) unsigned int*)l, 16, 0, 0);
}

// ---------------- fp32 -> bf16 elementwise convert (8 elems/thread) --------
__global__ __launch_bounds__(256) void cvt_bf16(
    const float* __restrict__ in, unsigned short* __restrict__ out) {
  const size_t id = (size_t)blockIdx.x * 256 + threadIdx.x;
  const float4 a = *(const float4*)&in[id * 8];
  const float4 c = *(const float4*)&in[id * 8 + 4];
  u16x8 o;
  o[0] = f2bf(a.x); o[1] = f2bf(a.y); o[2] = f2bf(a.z); o[3] = f2bf(a.w);
  o[4] = f2bf(c.x); o[5] = f2bf(c.y); o[6] = f2bf(c.z); o[7] = f2bf(c.w);
  *(u16x8*)&out[id * 8] = o;
}

// ---------------- W[K][N] f32  ->  Wt[N][K] bf16 (32x32 LDS tiles) ---------
__global__ __launch_bounds__(256) void transpose_cvt(
    const float* __restrict__ W, unsigned short* __restrict__ Wt, int K, int N) {
  __shared__ unsigned short tile[32][33];
  const int n0 = blockIdx.x * 32, k0 = blockIdx.y * 32;
  const int t = threadIdx.x;
  const int r = t >> 3, c4 = (t & 7) * 4;
  const float4 v = *(const float4*)&W[(size_t)(k0 + r) * N + n0 + c4];
  tile[r][c4 + 0] = f2bf(v.x);
  tile[r][c4 + 1] = f2bf(v.y);
  tile[r][c4 + 2] = f2bf(v.z);
  tile[r][c4 + 3] = f2bf(v.w);
  __syncthreads();
  u16x4 o;
  #pragma unroll
  for (int i = 0; i < 4; ++i) o[i] = tile[c4 + i][r];
  *(u16x4*)&Wt[(size_t)(n0 + r) * K + k0 + c4] = o;
}

// ---------------- 256^2 4-phase/K-tile bf16 MFMA GEMM (m201-style) ---------
// A [M][K], Bt [N][K] bf16 row-major. 512 thr = 8 waves (2Mx4N), 128x64/wave.
// BK=64; LDS 128KiB = 2 dbuf x { A: 2 halves 128x64, B: 2 halves 128x64 }.
// Per tile 4 phases (C-quadrants), each: {ds_read subtile || stage half-tile
// -> BAR -> lgkmcnt(0)+sched_barrier -> setprio(1) 16xMFMA setprio(0) -> BAR}.
// Stage schedule: q0: B-h0(t+1), q1: B-h1(t+1), q3: A-h0+A-h1(t+2)+vmcnt(4)
// (every target dead >=1 closing-barrier before issue; counted vmcnt retires
// exactly tile t+1; 2 half-tiles stay in flight; drain only at NT-2).
// Swizzle: 128B rows, 16B slot = colgrp ^ (row&7)  (row*128 contributes no
// bank bits -> perfectly balanced, 2-way floor). Stage decode: linear LDS dst
// t*16, source colgrp cg = (t&7)^((t>>3)&7), rows t>>3 and t>>3+64.
// ACT: 0 none->f32, 1 silu->bf16, 2 sigmoid->bf16.
template<int ACT>
__global__ __launch_bounds__(512, 2) void gemm256(
    const unsigned short* __restrict__ A, const unsigned short* __restrict__ Bt,
    void* __restrict__ C, int M, int N, int K) {
  __shared__ unsigned short lds[65536];          // 128 KiB
  char* ldsb = (char*)lds;
  const int t = threadIdx.x;
  const int lane = t & 63, wave = t >> 6;
  const int wr = wave >> 2, wc = wave & 3;       // 2 x 4 wave grid
  const int l15 = lane & 15;

  // XCD-patched block swizzle: XCD x owns a bm-stripe, bn-major inside
  const int nbm = M >> 8, nbn = N >> 8;
  const int nbmx = nbm >> 3;
  const int xcd = blockIdx.x & 7, q = blockIdx.x >> 3;
  const int bm = xcd * nbmx + (q % nbmx);
  const int bn = q / nbmx;

  // ---- staging sources (swizzle-decoded) ----
  const int cg = (t & 7) ^ ((t >> 3) & 7);
  const unsigned short* sA = A  + (size_t)(bm * 256 + (t >> 3)) * K + cg * 8;
  const unsigned short* sB = Bt + (size_t)(bn * 256 + (t >> 3)) * K + cg * 8;

  // ---- ds_read slot bytes (kk = 0/1) ----
  const int s0 = (((lane >> 4) ^ (lane & 7)) << 4);
  const int s1 = (((4 + (lane >> 4)) ^ (lane & 7)) << 4);
  const int rB0 = (wc & 1) * 64 + l15;           // B row-in-half base
  const int hbB = 32768 + (wc >> 1) * 16384;     // B half base (bytes)
  const int haA = wr * 16384;                    // A half base (bytes)

  #define STG(bufi, isB, h, uu) {                                          \
    char* _d = ldsb + ((bufi) << 16) + ((isB) ? 32768 : 0) + (h) * 16384 + (t << 4); \
    const unsigned short* _s = ((isB) ? sB : sA) + (size_t)((h) * 128) * K + (size_t)(uu) * 64; \
    gload16(_s, _d); gload16(_s + (size_t)64 * K, _d + 8192); }

  const int NT = K >> 6;                         // K=2048 -> 32 tiles
  // prologue: tile0 all 4 half-tiles + tile1's A halves (= virtual t=-1 q3)
  STG(0, 0, 0, 0); STG(0, 0, 1, 0); STG(0, 1, 0, 0); STG(0, 1, 1, 0);
  STG(1, 0, 0, 1); STG(1, 0, 1, 1);
  asm volatile("s_waitcnt vmcnt(4)" ::: "memory");   // tile0 landed
  __builtin_amdgcn_s_barrier();

  f32x4 acc[8][4] = {};
  for (int u = 0; u < NT; ++u) {
    const int base = (u & 1) << 16;
    const int nb = ((u + 1) & 1);
    bf16x8 af[4][2], bf0[2][2], bf1[2][2];
    // -------- q0: m-lo x n-lo ; reads af-lo(8) + bf0(4) ; stage B-h0(u+1)
    #pragma unroll
    for (int m = 0; m < 4; ++m) {
      const int rb = base + haA + (m * 16 + l15) * 128;
      af[m][0] = *(const bf16x8*)(ldsb + rb + s0);
      af[m][1] = *(const bf16x8*)(ldsb + rb + s1);
    }
    #pragma unroll
    for (int n = 0; n < 2; ++n) {
      const int rb = base + hbB + (rB0 + n * 16) * 128;
      bf0[n][0] = *(const bf16x8*)(ldsb + rb + s0);
      bf0[n][1] = *(const bf16x8*)(ldsb + rb + s1);
    }
    if (u + 1 < NT) STG(nb, 1, 0, u + 1);
    __builtin_amdgcn_s_barrier();
    asm volatile("s_waitcnt lgkmcnt(0)" ::: "memory");
    __builtin_amdgcn_sched_barrier(0);
    __builtin_amdgcn_s_setprio(1);
    #pragma unroll
    for (int m = 0; m < 4; ++m)
      #pragma unroll
      for (int n = 0; n < 2; ++n)
        #pragma unroll
        for (int kk = 0; kk < 2; ++kk)
          acc[m][n] = __builtin_amdgcn_mfma_f32_16x16x32_bf16(af[m][kk], bf0[n][kk], acc[m][n], 0, 0, 0);
    __builtin_amdgcn_s_setprio(0);
    __builtin_amdgcn_s_barrier();
    // -------- q1: m-lo x n-hi ; reads bf1(4) ; stage B-h1(u+1)
    #pragma unroll
    for (int n = 0; n < 2; ++n) {
      const int rb = base + hbB + (rB0 + (2 + n) * 16) * 128;
      bf1[n][0] = *(const bf16x8*)(ldsb + rb + s0);
      bf1[n][1] = *(const bf16x8*)(ldsb + rb + s1);
    }
    if (u + 1 < NT) STG(nb, 1, 1, u + 1);
    __builtin_amdgcn_s_barrier();
    asm volatile("s_waitcnt lgkmcnt(0)" ::: "memory");
    __builtin_amdgcn_sched_barrier(0);
    __builtin_amdgcn_s_setprio(1);
    #pragma unroll
    for (int m = 0; m < 4; ++m)
      #pragma unroll
      for (int n = 0; n < 2; ++n)
        #pragma unroll
        for (int kk = 0; kk < 2; ++kk)
          acc[m][2 + n] = __builtin_amdgcn_mfma_f32_16x16x32_bf16(af[m][kk], bf1[n][kk], acc[m][2 + n], 0, 0, 0);
    __builtin_amdgcn_s_setprio(0);
    __builtin_amdgcn_s_barrier();
    // -------- q2: m-hi x n-lo ; reads af-hi(8)
    #pragma unroll
    for (int m = 0; m < 4; ++m) {
      const int rb = base + haA + ((4 + m) * 16 + l15) * 128;
      af[m][0] = *(const bf16x8*)(ldsb + rb + s0);
      af[m][1] = *(const bf16x8*)(ldsb + rb + s1);
    }
    __builtin_amdgcn_s_barrier();
    asm volatile("s_waitcnt lgkmcnt(0)" ::: "memory");
    __builtin_amdgcn_sched_barrier(0);
    __builtin_amdgcn_s_setprio(1);
    #pragma unroll
    for (int m = 0; m < 4; ++m)
      #pragma unroll
      for (int n = 0; n < 2; ++n)
        #pragma unroll
        for (int kk = 0; kk < 2; ++kk)
          acc[4 + m][n] = __builtin_amdgcn_mfma_f32_16x16x32_bf16(af[m][kk], bf0[n][kk], acc[4 + m][n], 0, 0, 0);
    __builtin_amdgcn_s_setprio(0);
    __builtin_amdgcn_s_barrier();
    // -------- q3: m-hi x n-hi ; stage A-h0+A-h1(u+2); counted vmcnt
    if (u + 2 < NT) { STG((u & 1), 0, 0, u + 2); STG((u & 1), 0, 1, u + 2); }
    if (u < NT - 2) asm volatile("s_waitcnt vmcnt(4)" ::: "memory");
    else            asm volatile("s_waitcnt vmcnt(0)" ::: "memory");
    __builtin_amdgcn_s_barrier();
    __builtin_amdgcn_s_setprio(1);
    #pragma unroll
    for (int m = 0; m < 4; ++m)
      #pragma unroll
      for (int n = 0; n < 2; ++n)
        #pragma unroll
        for (int kk = 0; kk < 2; ++kk)
          acc[4 + m][2 + n] = __builtin_amdgcn_mfma_f32_16x16x32_bf16(af[m][kk], bf1[n][kk], acc[4 + m][2 + n], 0, 0, 0);
    __builtin_amdgcn_s_setprio(0);
    __builtin_amdgcn_s_barrier();
  }
  #undef STG

  // epilogue: C/D layout col = lane&15, row = (lane>>4)*4 + reg  [m89-verified]
  const int ro = (lane >> 4) * 4, co = lane & 15;
  #pragma unroll
  for (int m = 0; m < 8; ++m)
    #pragma unroll
    for (int n = 0; n < 4; ++n) {
      const int gc = bn * 256 + wc * 64 + n * 16 + co;
      #pragma unroll
      for (int r = 0; r < 4; ++r) {
        const int gr = bm * 256 + wr * 128 + m * 16 + ro + r;
        float v = acc[m][n][r];
        if constexpr (ACT == 1) v = v / (1.f + __expf(-v));     // silu
        if constexpr (ACT == 2) v = 1.f / (1.f + __expf(-v));   // sigmoid
        if constexpr (ACT == 0) ((float*)C)[(size_t)gr * N + gc] = v;
        else ((unsigned short*)C)[(size_t)gr * N + gc] = f2bf(v);
      }
    }
}

// ---------------- per-block KV outer product, TRANSPOSED out ---------------
// st[(bh*NBL+j)][f][e] = sum_m (k[m][e]*kdecay[m]) * v[m][f]   (bf16)
__global__ __launch_bounds__(256) void kv_outer(
    const unsigned short* __restrict__ qkv, unsigned short* __restrict__ st) {
  const int gid = blockIdx.x;
  const int j = gid & 15;
  const int bh = gid >> 4;
  const int h = bh & 15;
  const int b = bh >> 4;
  const float slope = exp2f(-0.5f * (float)(h + 1));
  const int t = threadIdx.x;
  __shared__ unsigned short kl[64][136];
  __shared__ unsigned short vl[64][136];
  float acc[8][8] = {};
  const int e0 = (t >> 4) * 8, f0 = (t & 15) * 8;
  for (int ch = 0; ch < 4; ++ch) {
    if (ch) __syncthreads();
    #pragma unroll
    for (int i = 0; i < 4; ++i) {
      const int cc = t + 256 * i;
      const int r = cc >> 4, c0 = (cc & 15) * 8;
      const int mb = ch * 64 + r;
      const int seq = b * S + j * BLK + mb;
      const u16x8 k8 = *(const u16x8*)&qkv[(size_t)seq * NQKV + h * 384 + 128 + c0];
      const float kd = expf(-slope * (float)(255 - mb));
      u16x8 kw;
      #pragma unroll
      for (int q2 = 0; q2 < 8; ++q2) kw[q2] = f2bf(bf2f(k8[q2]) * kd);
      *(u16x8*)&kl[r][c0] = kw;
      *(u16x8*)&vl[r][c0] = *(const u16x8*)&qkv[(size_t)seq * NQKV + h * 384 + 256 + c0];
    }
    __syncthreads();
    for (int m = 0; m < 64; ++m) {
      const u16x8 k8 = *(const u16x8*)&kl[m][e0];
      const u16x8 v8 = *(const u16x8*)&vl[m][f0];
      float kf[8], vf[8];
      #pragma unroll
      for (int q2 = 0; q2 < 8; ++q2) { kf[q2] = bf2f(k8[q2]); vf[q2] = bf2f(v8[q2]); }
      #pragma unroll
      for (int i = 0; i < 8; ++i)
        #pragma unroll
        for (int q2 = 0; q2 < 8; ++q2) acc[i][q2] += kf[i] * vf[q2];
    }
  }
  const size_t base = (size_t)gid * (D * D);
  #pragma unroll
  for (int q2 = 0; q2 < 8; ++q2) {           // transposed: st[f][e]
    u16x8 ow;
    #pragma unroll
    for (int i = 0; i < 8; ++i) ow[i] = f2bf(acc[i][q2]);
    *(u16x8*)&st[base + (size_t)(f0 + q2) * D + e0] = ow;
  }
}

// ---------------- exclusive decay scan over blocks (per element) -----------
__global__ __launch_bounds__(256) void kv_scan(unsigned short* __restrict__ st) {
  const int id = blockIdx.x * 256 + threadIdx.x;  // NB*H*D*D threads
  const int ef = id & (D * D - 1);
  const int bh = id >> 14;
  const int h = bh & 15;
  const float slope = exp2f(-0.5f * (float)(h + 1));
  const float bd = expf(-slope * 256.f);
  unsigned short* p = st + (size_t)bh * NBL * D * D + ef;
  float cur = 0.f;
  #pragma unroll
  for (int jj = 0; jj < NBL; ++jj) {
    const float m = bf2f(p[(size_t)jj * D * D]);
    p[(size_t)jj * D * D] = f2bf(cur);
    cur = bd * cur + m;
  }
}

// ---------------- MFMA attention -------------------------------------------
// grid = ((b*H+h)*NBL + j)*2 + half ; WG = 4 waves, 128 q-rows x 128 dims.
// out = qdecay.*(q @ kvT^T) + (mask(q@k^T).*decay) @ v
__global__ __launch_bounds__(256) void attn_mfma(
    const unsigned short* __restrict__ qkv, const unsigned short* __restrict__ st,
    unsigned short* __restrict__ ob) {
  const int gid = blockIdx.x;
  const int half = gid & 1;
  const int rest = gid >> 1;
  const int j = rest & 15;
  const int bh = rest >> 4;
  const int h = bh & 15;
  const int b = bh >> 4;
  const float slope = exp2f(-0.5f * (float)(h + 1));
  const int t = threadIdx.x;
  const int lane = t & 63, wave = t >> 6, wr = wave >> 1, wc = wave & 1;

  __shared__ unsigned short ql[128][136];   // q rows (m x e)
  __shared__ unsigned short cb[128][136];   // kvT / k / vT chunk buffer
  __shared__ unsigned short pl[128][136];   // decayed P (m x m') bf16

  // stage q and kvT (state is pre-transposed [f][e], exclusive-scanned)
  {
    const int r = t >> 4, c0 = (t & 15) * 8;
    const size_t stbase = (size_t)rest * (D * D);
    #pragma unroll
    for (int p = 0; p < 8; ++p) {
      const int seq = b * S + j * BLK + half * 128 + r + p * 16;
      *(u16x8*)&ql[r + p * 16][c0] = *(const u16x8*)&qkv[(size_t)seq * NQKV + h * 384 + c0];
      *(u16x8*)&cb[r + p * 16][c0] = *(const u16x8*)&st[stbase + (size_t)(r + p * 16) * D + c0];
    }
  }
  __syncthreads();

  f32x4 acc[4][4] = {};
  // ---- phase 1: non-diag = q @ kvT^T ----
  #pragma unroll
  for (int kk = 0; kk < 4; ++kk) {
    bf16x8 af[4], bfr[4];
    #pragma unroll
    for (int m = 0; m < 4; ++m)
      af[m] = *(const bf16x8*)&ql[wr * 64 + m * 16 + (lane & 15)][kk * 32 + (lane >> 4) * 8];
    #pragma unroll
    for (int n = 0; n < 4; ++n)
      bfr[n] = *(const bf16x8*)&cb[wc * 64 + n * 16 + (lane & 15)][kk * 32 + (lane >> 4) * 8];
    #pragma unroll
    for (int m = 0; m < 4; ++m)
      #pragma unroll
      for (int n = 0; n < 4; ++n)
        acc[m][n] = __builtin_amdgcn_mfma_f32_16x16x32_bf16(af[m], bfr[n], acc[m][n], 0, 0, 0);
  }
  // apply q_decay = exp(-slope*(gm+1)) to the non-diag part
  const int ro = (lane >> 4) * 4;
  #pragma unroll
  for (int m = 0; m < 4; ++m)
    #pragma unroll
    for (int r = 0; r < 4; ++r) {
      const int gm = half * 128 + wr * 64 + m * 16 + ro + r;
      const float qd = expf(-slope * (float)(gm + 1));
      #pragma unroll
      for (int n = 0; n < 4; ++n) acc[m][n][r] *= qd;
    }

  // ---- phase 2: intra-block causal, chunks of 128 k-rows ----
  const int nch = 1 + half;
  for (int c = 0; c < nch; ++c) {
    __syncthreads();                         // cb free (prev readers done)
    {
      const int r = t >> 4, c0 = (t & 15) * 8;
      #pragma unroll
      for (int p = 0; p < 8; ++p) {
        const int seq = b * S + j * BLK + c * 128 + r + p * 16;
        *(u16x8*)&cb[r + p * 16][c0] = *(const u16x8*)&qkv[(size_t)seq * NQKV + h * 384 + 128 + c0];
      }
    }
    __syncthreads();
    f32x4 sacc[4][4] = {};
    #pragma unroll
    for (int kk = 0; kk < 4; ++kk) {
      bf16x8 af[4], bfr[4];
      #pragma unroll
      for (int m = 0; m < 4; ++m)
        af[m] = *(const bf16x8*)&ql[wr * 64 + m * 16 + (lane & 15)][kk * 32 + (lane >> 4) * 8];
      #pragma unroll
      for (int n = 0; n < 4; ++n)
        bfr[n] = *(const bf16x8*)&cb[wc * 64 + n * 16 + (lane & 15)][kk * 32 + (lane >> 4) * 8];
      #pragma unroll
      for (int m = 0; m < 4; ++m)
        #pragma unroll
        for (int n = 0; n < 4; ++n)
          sacc[m][n] = __builtin_amdgcn_mfma_f32_16x16x32_bf16(af[m], bfr[n], sacc[m][n], 0, 0, 0);
    }
    // decay+mask -> P (bf16) in LDS
    #pragma unroll
    for (int m = 0; m < 4; ++m)
      #pragma unroll
      for (int n = 0; n < 4; ++n) {
        const int lc = wc * 64 + n * 16 + (lane & 15);
        const int gp = c * 128 + lc;
        #pragma unroll
        for (int r = 0; r < 4; ++r) {
          const int lm = wr * 64 + m * 16 + ro + r;
          const int gm = half * 128 + lm;
          const float dd = (gm >= gp) ? expf(-slope * (float)(gm - gp)) : 0.f;
          pl[lm][lc] = f2bf(sacc[m][n][r] * dd);
        }
      }
    __syncthreads();                         // P complete; cb readers done
    // stage v transposed: cb[f][m']
    {
      const int vr = t & 15, vc0 = (t >> 4) * 8;
      #pragma unroll
      for (int p = 0; p < 8; ++p) {
        const int row = vr + p * 16;
        const int seq = b * S + j * BLK + c * 128 + row;
        const u16x8 vv = *(const u16x8*)&qkv[(size_t)seq * NQKV + h * 384 + 256 + vc0];
        #pragma unroll
        for (int i = 0; i < 8; ++i) cb[vc0 + i][row] = vv[i];
      }
    }
    __syncthreads();
    // PV: acc += P @ vT^T
    #pragma unroll
    for (int kk = 0; kk < 4; ++kk) {
      bf16x8 af[4], bfr[4];
      #pragma unroll
      for (int m = 0; m < 4; ++m)
        af[m] = *(const bf16x8*)&pl[wr * 64 + m * 16 + (lane & 15)][kk * 32 + (lane >> 4) * 8];
      #pragma unroll
      for (int n = 0; n < 4; ++n)
        bfr[n] = *(const bf16x8*)&cb[wc * 64 + n * 16 + (lane & 15)][kk * 32 + (lane >> 4) * 8];
      #pragma unroll
      for (int m = 0; m < 4; ++m)
        #pragma unroll
        for (int n = 0; n < 4; ++n)
          acc[m][n] = __builtin_amdgcn_mfma_f32_16x16x32_bf16(af[m], bfr[n], acc[m][n], 0, 0, 0);
    }
  }

  // epilogue: ob[b][n][h*D + f]
  #pragma unroll
  for (int m = 0; m < 4; ++m)
    #pragma unroll
    for (int n = 0; n < 4; ++n) {
      const int fc = h * D + wc * 64 + n * 16 + (lane & 15);
      #pragma unroll
      for (int r = 0; r < 4; ++r) {
        const int seq = b * S + j * BLK + half * 128 + wr * 64 + m * 16 + ro + r;
        ob[(size_t)seq * HD + fc] = f2bf(acc[m][n][r]);
      }
    }
}

// ---------------- RMSNorm * norm_w * sigmoid-gate -> bf16 ------------------
__global__ __launch_bounds__(256) void norm_gate(
    const unsigned short* __restrict__ ob, const unsigned short* __restrict__ gb,
    const float* __restrict__ nw, unsigned short* __restrict__ og) {
  const int row = blockIdx.x;
  const int t = threadIdx.x;
  const u16x8 ov = *(const u16x8*)&ob[(size_t)row * HD + t * 8];
  float f[8];
  float ss = 0.f;
  #pragma unroll
  for (int i = 0; i < 8; ++i) { f[i] = bf2f(ov[i]); ss += f[i] * f[i]; }
  #pragma unroll
  for (int off = 32; off > 0; off >>= 1) ss += __shfl_down(ss, off, 64);
  __shared__ float red[4];
  if ((t & 63) == 0) red[t >> 6] = ss;
  __syncthreads();
  const float rms = rsqrtf((red[0] + red[1] + red[2] + red[3]) * (1.f / HD) + 1e-6f);
  const u16x8 gv = *(const u16x8*)&gb[(size_t)row * HD + t * 8];
  u16x8 ow;
  #pragma unroll
  for (int i = 0; i < 8; ++i)
    ow[i] = f2bf(f[i] * rms * nw[t * 8 + i] * bf2f(gv[i]));
  *(u16x8*)&og[(size_t)row * HD + t * 8] = ow;
}

extern "C" void kernel_launch(void* const* d_in, const int* in_sizes, int n_in,
                              void* d_out, int out_size, void* d_ws, size_t ws_size,
                              hipStream_t stream) {
  (void)in_sizes; (void)n_in; (void)out_size; (void)ws_size;
  const float* x    = (const float*)d_in[0];
  const float* Wqkv = (const float*)d_in[1];
  const float* Wg   = (const float*)d_in[2];
  const float* Wout = (const float*)d_in[3];
  const float* nw   = (const float*)d_in[4];

  char* ws = (char*)d_ws;
  unsigned short* xb    = (unsigned short*)ws; ws += SZ_XB;
  unsigned short* wqkvt = (unsigned short*)ws; ws += SZ_WQKVT;
  unsigned short* wgt   = (unsigned short*)ws; ws += SZ_WGT;
  unsigned short* woutt = (unsigned short*)ws; ws += SZ_WOUTT;
  unsigned short* qkvb  = (unsigned short*)ws; ws += SZ_QKVB;
  unsigned short* gb    = (unsigned short*)ws; ws += SZ_GB;
  unsigned short* st    = (unsigned short*)ws; ws += SZ_ST;
  unsigned short* ob    = (unsigned short*)ws; ws += SZ_OB;
  unsigned short* og    = xb;  // alias: xb dead after the gate GEMM

  cvt_bf16<<<dim3((NB * S * DIN) / (256 * 8)), 256, 0, stream>>>(x, xb);
  transpose_cvt<<<dim3(NQKV / 32, DIN / 32), 256, 0, stream>>>(Wqkv, wqkvt, DIN, NQKV);
  transpose_cvt<<<dim3(HD / 32, DIN / 32), 256, 0, stream>>>(Wg, wgt, DIN, HD);
  transpose_cvt<<<dim3(HD / 32, HD / 32), 256, 0, stream>>>(Wout, woutt, HD, HD);

  // qkv = silu(x @ Wqkv), gate = sigmoid(x @ Wg)
  gemm256<1><<<dim3((NB * S / 256) * (NQKV / 256)), 512, 0, stream>>>(xb, wqkvt, qkvb, NB * S, NQKV, DIN);
  gemm256<2><<<dim3((NB * S / 256) * (HD / 256)), 512, 0, stream>>>(xb, wgt, gb, NB * S, HD, DIN);

  kv_outer<<<dim3(NB * H * NBL), 256, 0, stream>>>(qkvb, st);
  kv_scan<<<dim3((NB * H * D * D) / 256), 256, 0, stream>>>(st);
  attn_mfma<<<dim3(NB * H * NBL * 2), 256, 0, stream>>>(qkvb, st, ob);

  norm_gate<<<dim3(NB * S), 256, 0, stream>>>(ob, gb, nw, og);
  gemm256<0><<<dim3((NB * S / 256) * (HD / 256)), 512, 0, stream>>>(og, woutt, d_out, NB * S, HD, HD);
}

// Round 6
// 524.040 us; speedup vs baseline: 1.0435x; 1.0135x over previous
//
#include <hip/hip_runtime.h>
#include <cstddef>

typedef float f32x4 __attribute__((ext_vector_type(4)));
typedef __bf16 bf16x8 __attribute__((ext_vector_type(8)));
typedef unsigned short u16x8 __attribute__((ext_vector_type(8)));
typedef unsigned short u16x4 __attribute__((ext_vector_type(4)));

constexpr int NB = 2, S = 4096, H = 16, D = 128;
constexpr int DIN = 2048, NQKV = 6144, HD = 2048;
constexpr int BLK = 256, NBL = 16;

constexpr size_t SZ_XB    = (size_t)NB * S * DIN * 2;
constexpr size_t SZ_WQKVT = (size_t)NQKV * DIN * 2;
constexpr size_t SZ_WGT   = (size_t)HD * DIN * 2;
constexpr size_t SZ_WOUTT = (size_t)HD * HD * 2;
constexpr size_t SZ_QKVB  = (size_t)NB * S * NQKV * 2;
constexpr size_t SZ_GB    = (size_t)NB * S * HD * 2;
constexpr size_t SZ_ST    = (size_t)NB * H * NBL * D * D * 2;
constexpr size_t SZ_OB    = (size_t)NB * S * HD * 2;

__device__ __forceinline__ float bf2f(unsigned short u) {
  return __uint_as_float(((unsigned)u) << 16);
}
__device__ __forceinline__ unsigned short f2bf(float f) {
  unsigned u = __float_as_uint(f);
  u += 0x7fffu + ((u >> 16) & 1u);
  return (unsigned short)(u >> 16);
}
__device__ __forceinline__ void gload16(const void* g, void* l) {
  __builtin_amdgcn_global_load_lds(
      (const __attribute__((address_space(1))) unsigned int*)g,
      (__attribute__((address_space(3))) unsigned int*)l, 16, 0, 0);
}

// ---------------- fp32 -> bf16 elementwise convert (8 elems/thread) --------
__global__ __launch_bounds__(256) void cvt_bf16(
    const float* __restrict__ in, unsigned short* __restrict__ out) {
  const size_t id = (size_t)blockIdx.x * 256 + threadIdx.x;
  const float4 a = *(const float4*)&in[id * 8];
  const float4 c = *(const float4*)&in[id * 8 + 4];
  u16x8 o;
  o[0] = f2bf(a.x); o[1] = f2bf(a.y); o[2] = f2bf(a.z); o[3] = f2bf(a.w);
  o[4] = f2bf(c.x); o[5] = f2bf(c.y); o[6] = f2bf(c.z); o[7] = f2bf(c.w);
  *(u16x8*)&out[id * 8] = o;
}

// ---------------- W[K][N] f32  ->  Wt[N][K] bf16 (32x32 LDS tiles) ---------
__global__ __launch_bounds__(256) void transpose_cvt(
    const float* __restrict__ W, unsigned short* __restrict__ Wt, int K, int N) {
  __shared__ unsigned short tile[32][33];
  const int n0 = blockIdx.x * 32, k0 = blockIdx.y * 32;
  const int t = threadIdx.x;
  const int r = t >> 3, c4 = (t & 7) * 4;
  const float4 v = *(const float4*)&W[(size_t)(k0 + r) * N + n0 + c4];
  tile[r][c4 + 0] = f2bf(v.x);
  tile[r][c4 + 1] = f2bf(v.y);
  tile[r][c4 + 2] = f2bf(v.z);
  tile[r][c4 + 3] = f2bf(v.w);
  __syncthreads();
  u16x4 o;
  #pragma unroll
  for (int i = 0; i < 4; ++i) o[i] = tile[c4 + i][r];
  *(u16x4*)&Wt[(size_t)(n0 + r) * K + k0 + c4] = o;
}

// ---------------- 128^2 m97-structure bf16 MFMA GEMM -----------------------
// A [M][K], Bt [N][K] bf16 row-major. 256 thr = 4 waves (2Mx2N), 64x64/wave.
// BK=64, SINGLE 32 KiB LDS buffer, 2-barrier loop + vmcnt(0) drain; 3
// blocks/CU (launch_bounds(256,3)) provide implicit cross-block overlap
// (m114/m97: resident-block slip covers the drain stall).
// Staging: line-coalesced (8 lanes/row -> full 128B lines). Swizzle: 16B
// slot = colgrp ^ (row&7) (row*128 contributes no bank bits -> 2-way floor);
// linear LDS dst t*16, pre-swizzled global source cg=(t&7)^((t>>3)&7).
// ACT: 0 -> f32 into O1 (stride N); 3 -> fused: gc<NSPLIT silu->O1 bf16
// (stride NSPLIT), else sigmoid->O2 bf16 (stride N-NSPLIT). Split is
// block-uniform (NSPLIT % 128 == 0).
template<int ACT>
__global__ __launch_bounds__(256, 3) void gemm128(
    const unsigned short* __restrict__ A, const unsigned short* __restrict__ Bt,
    void* __restrict__ O1, void* __restrict__ O2,
    int M, int N, int K, int NSPLIT) {
  __shared__ unsigned short lds[16384];          // 32 KiB: A 16K + B 16K
  char* ldsb = (char*)lds;
  const int t = threadIdx.x;
  const int lane = t & 63, wave = t >> 6;
  const int wr = wave >> 1, wc = wave & 1;
  const int l15 = lane & 15;

  // XCD bm-stripe swizzle: XCD x owns bm in [x*nbm/8, (x+1)*nbm/8), bn-major
  const int nbm = M >> 7;
  const int nbmx = nbm >> 3;
  const int xcd = blockIdx.x & 7, q = blockIdx.x >> 3;
  const int bm = xcd * nbmx + (q % nbmx);
  const int bn = q / nbmx;

  // staging source (swizzle-decoded): thread t covers row t>>3 (+i*32),
  // col-grp cg within the unit's 64-col span
  const int cg = (t & 7) ^ ((t >> 3) & 7);
  const unsigned short* sA = A  + (size_t)(bm * 128 + (t >> 3)) * K + cg * 8;
  const unsigned short* sB = Bt + (size_t)(bn * 128 + (t >> 3)) * K + cg * 8;
  const int dstb = t << 4;                       // linear 16B per thread

  // ds_read byte offsets (swizzled): slot = (kk*4 + lane>>4) ^ (row&7)
  int offA[2][4], offB[2][4];
  #pragma unroll
  for (int kk = 0; kk < 2; ++kk) {
    #pragma unroll
    for (int m = 0; m < 4; ++m) {
      const int row = wr * 64 + m * 16 + l15;
      offA[kk][m] = row * 128 + (((kk * 4 + (lane >> 4)) ^ (row & 7)) << 4);
    }
    #pragma unroll
    for (int n = 0; n < 4; ++n) {
      const int row = wc * 64 + n * 16 + l15;
      offB[kk][n] = 16384 + row * 128 + (((kk * 4 + (lane >> 4)) ^ (row & 7)) << 4);
    }
  }

  const int NT = K >> 6;                         // K=2048 -> 32 units
  f32x4 acc[4][4] = {};
  for (int u = 0; u < NT; ++u) {
    __syncthreads();                             // prev readers retired
    const int ko = u * 64;
    #pragma unroll
    for (int i = 0; i < 4; ++i) {
      gload16(sA + (size_t)(i * 32) * K + ko, ldsb + i * 4096 + dstb);
      gload16(sB + (size_t)(i * 32) * K + ko, ldsb + 16384 + i * 4096 + dstb);
    }
    asm volatile("s_waitcnt vmcnt(0)" ::: "memory");
    __syncthreads();
    #pragma unroll
    for (int kk = 0; kk < 2; ++kk) {
      bf16x8 af[4], bfr[4];
      #pragma unroll
      for (int m = 0; m < 4; ++m) af[m] = *(const bf16x8*)(ldsb + offA[kk][m]);
      #pragma unroll
      for (int n = 0; n < 4; ++n) bfr[n] = *(const bf16x8*)(ldsb + offB[kk][n]);
      #pragma unroll
      for (int m = 0; m < 4; ++m)
        #pragma unroll
        for (int n = 0; n < 4; ++n)
          acc[m][n] = __builtin_amdgcn_mfma_f32_16x16x32_bf16(af[m], bfr[n], acc[m][n], 0, 0, 0);
    }
  }

  // epilogue: C/D layout col = lane&15, row = (lane>>4)*4 + reg  [m89-verified]
  const int ro = (lane >> 4) * 4, co = l15;
  const bool lo = (bn * 128) < NSPLIT;           // block-uniform split
  #pragma unroll
  for (int m = 0; m < 4; ++m)
    #pragma unroll
    for (int n = 0; n < 4; ++n) {
      const int gc = bn * 128 + wc * 64 + n * 16 + co;
      #pragma unroll
      for (int r = 0; r < 4; ++r) {
        const int gr = bm * 128 + wr * 64 + m * 16 + ro + r;
        float v = acc[m][n][r];
        if constexpr (ACT == 0) {
          ((float*)O1)[(size_t)gr * N + gc] = v;
        } else {
          if (lo) {
            v = v / (1.f + __expf(-v));          // silu
            ((unsigned short*)O1)[(size_t)gr * NSPLIT + gc] = f2bf(v);
          } else {
            v = 1.f / (1.f + __expf(-v));        // sigmoid
            ((unsigned short*)O2)[(size_t)gr * (N - NSPLIT) + (gc - NSPLIT)] = f2bf(v);
          }
        }
      }
    }
}

// ---------------- per-block KV outer product, TRANSPOSED out ---------------
// st[(bh*NBL+j)][f][e] = sum_m (k[m][e]*kdecay[m]) * v[m][f]   (bf16)
__global__ __launch_bounds__(256) void kv_outer(
    const unsigned short* __restrict__ qkv, unsigned short* __restrict__ st) {
  const int gid = blockIdx.x;
  const int j = gid & 15;
  const int bh = gid >> 4;
  const int h = bh & 15;
  const int b = bh >> 4;
  const float slope = exp2f(-0.5f * (float)(h + 1));
  const int t = threadIdx.x;
  __shared__ unsigned short kl[64][136];
  __shared__ unsigned short vl[64][136];
  float acc[8][8] = {};
  const int e0 = (t >> 4) * 8, f0 = (t & 15) * 8;
  for (int ch = 0; ch < 4; ++ch) {
    if (ch) __syncthreads();
    #pragma unroll
    for (int i = 0; i < 4; ++i) {
      const int cc = t + 256 * i;
      const int r = cc >> 4, c0 = (cc & 15) * 8;
      const int mb = ch * 64 + r;
      const int seq = b * S + j * BLK + mb;
      const u16x8 k8 = *(const u16x8*)&qkv[(size_t)seq * NQKV + h * 384 + 128 + c0];
      const float kd = expf(-slope * (float)(255 - mb));
      u16x8 kw;
      #pragma unroll
      for (int q2 = 0; q2 < 8; ++q2) kw[q2] = f2bf(bf2f(k8[q2]) * kd);
      *(u16x8*)&kl[r][c0] = kw;
      *(u16x8*)&vl[r][c0] = *(const u16x8*)&qkv[(size_t)seq * NQKV + h * 384 + 256 + c0];
    }
    __syncthreads();
    for (int m = 0; m < 64; ++m) {
      const u16x8 k8 = *(const u16x8*)&kl[m][e0];
      const u16x8 v8 = *(const u16x8*)&vl[m][f0];
      float kf[8], vf[8];
      #pragma unroll
      for (int q2 = 0; q2 < 8; ++q2) { kf[q2] = bf2f(k8[q2]); vf[q2] = bf2f(v8[q2]); }
      #pragma unroll
      for (int i = 0; i < 8; ++i)
        #pragma unroll
        for (int q2 = 0; q2 < 8; ++q2) acc[i][q2] += kf[i] * vf[q2];
    }
  }
  const size_t base = (size_t)gid * (D * D);
  #pragma unroll
  for (int q2 = 0; q2 < 8; ++q2) {           // transposed: st[f][e]
    u16x8 ow;
    #pragma unroll
    for (int i = 0; i < 8; ++i) ow[i] = f2bf(acc[i][q2]);
    *(u16x8*)&st[base + (size_t)(f0 + q2) * D + e0] = ow;
  }
}

// ---------------- exclusive decay scan over blocks (per element) -----------
__global__ __launch_bounds__(256) void kv_scan(unsigned short* __restrict__ st) {
  const int id = blockIdx.x * 256 + threadIdx.x;  // NB*H*D*D threads
  const int ef = id & (D * D - 1);
  const int bh = id >> 14;
  const int h = bh & 15;
  const float slope = exp2f(-0.5f * (float)(h + 1));
  const float bd = expf(-slope * 256.f);
  unsigned short* p = st + (size_t)bh * NBL * D * D + ef;
  float cur = 0.f;
  #pragma unroll
  for (int jj = 0; jj < NBL; ++jj) {
    const float m = bf2f(p[(size_t)jj * D * D]);
    p[(size_t)jj * D * D] = f2bf(cur);
    cur = bd * cur + m;
  }
}

// ---------------- MFMA attention -------------------------------------------
// grid = ((b*H+h)*NBL + j)*2 + half ; WG = 4 waves, 128 q-rows x 128 dims.
// out = qdecay.*(q @ kvT^T) + (mask(q@k^T).*decay) @ v
__global__ __launch_bounds__(256) void attn_mfma(
    const unsigned short* __restrict__ qkv, const unsigned short* __restrict__ st,
    unsigned short* __restrict__ ob) {
  const int gid = blockIdx.x;
  const int half = gid & 1;
  const int rest = gid >> 1;
  const int j = rest & 15;
  const int bh = rest >> 4;
  const int h = bh & 15;
  const int b = bh >> 4;
  const float slope = exp2f(-0.5f * (float)(h + 1));
  const int t = threadIdx.x;
  const int lane = t & 63, wave = t >> 6, wr = wave >> 1, wc = wave & 1;

  __shared__ unsigned short ql[128][136];   // q rows (m x e)
  __shared__ unsigned short cb[128][136];   // kvT / k / vT chunk buffer
  __shared__ unsigned short pl[128][136];   // decayed P (m x m') bf16

  // stage q and kvT (state is pre-transposed [f][e], exclusive-scanned)
  {
    const int r = t >> 4, c0 = (t & 15) * 8;
    const size_t stbase = (size_t)rest * (D * D);
    #pragma unroll
    for (int p = 0; p < 8; ++p) {
      const int seq = b * S + j * BLK + half * 128 + r + p * 16;
      *(u16x8*)&ql[r + p * 16][c0] = *(const u16x8*)&qkv[(size_t)seq * NQKV + h * 384 + c0];
      *(u16x8*)&cb[r + p * 16][c0] = *(const u16x8*)&st[stbase + (size_t)(r + p * 16) * D + c0];
    }
  }
  __syncthreads();

  f32x4 acc[4][4] = {};
  // ---- phase 1: non-diag = q @ kvT^T ----
  #pragma unroll
  for (int kk = 0; kk < 4; ++kk) {
    bf16x8 af[4], bfr[4];
    #pragma unroll
    for (int m = 0; m < 4; ++m)
      af[m] = *(const bf16x8*)&ql[wr * 64 + m * 16 + (lane & 15)][kk * 32 + (lane >> 4) * 8];
    #pragma unroll
    for (int n = 0; n < 4; ++n)
      bfr[n] = *(const bf16x8*)&cb[wc * 64 + n * 16 + (lane & 15)][kk * 32 + (lane >> 4) * 8];
    #pragma unroll
    for (int m = 0; m < 4; ++m)
      #pragma unroll
      for (int n = 0; n < 4; ++n)
        acc[m][n] = __builtin_amdgcn_mfma_f32_16x16x32_bf16(af[m], bfr[n], acc[m][n], 0, 0, 0);
  }
  // apply q_decay = exp(-slope*(gm+1)) to the non-diag part
  const int ro = (lane >> 4) * 4;
  #pragma unroll
  for (int m = 0; m < 4; ++m)
    #pragma unroll
    for (int r = 0; r < 4; ++r) {
      const int gm = half * 128 + wr * 64 + m * 16 + ro + r;
      const float qd = expf(-slope * (float)(gm + 1));
      #pragma unroll
      for (int n = 0; n < 4; ++n) acc[m][n][r] *= qd;
    }

  // ---- phase 2: intra-block causal, chunks of 128 k-rows ----
  const int nch = 1 + half;
  for (int c = 0; c < nch; ++c) {
    __syncthreads();                         // cb free (prev readers done)
    {
      const int r = t >> 4, c0 = (t & 15) * 8;
      #pragma unroll
      for (int p = 0; p < 8; ++p) {
        const int seq = b * S + j * BLK + c * 128 + r + p * 16;
        *(u16x8*)&cb[r + p * 16][c0] = *(const u16x8*)&qkv[(size_t)seq * NQKV + h * 384 + 128 + c0];
      }
    }
    __syncthreads();
    f32x4 sacc[4][4] = {};
    #pragma unroll
    for (int kk = 0; kk < 4; ++kk) {
      bf16x8 af[4], bfr[4];
      #pragma unroll
      for (int m = 0; m < 4; ++m)
        af[m] = *(const bf16x8*)&ql[wr * 64 + m * 16 + (lane & 15)][kk * 32 + (lane >> 4) * 8];
      #pragma unroll
      for (int n = 0; n < 4; ++n)
        bfr[n] = *(const bf16x8*)&cb[wc * 64 + n * 16 + (lane & 15)][kk * 32 + (lane >> 4) * 8];
      #pragma unroll
      for (int m = 0; m < 4; ++m)
        #pragma unroll
        for (int n = 0; n < 4; ++n)
          sacc[m][n] = __builtin_amdgcn_mfma_f32_16x16x32_bf16(af[m], bfr[n], sacc[m][n], 0, 0, 0);
    }
    // decay+mask -> P (bf16) in LDS
    #pragma unroll
    for (int m = 0; m < 4; ++m)
      #pragma unroll
      for (int n = 0; n < 4; ++n) {
        const int lc = wc * 64 + n * 16 + (lane & 15);
        const int gp = c * 128 + lc;
        #pragma unroll
        for (int r = 0; r < 4; ++r) {
          const int lm = wr * 64 + m * 16 + ro + r;
          const int gm = half * 128 + lm;
          const float dd = (gm >= gp) ? expf(-slope * (float)(gm - gp)) : 0.f;
          pl[lm][lc] = f2bf(sacc[m][n][r] * dd);
        }
      }
    __syncthreads();                         // P complete; cb readers done
    // stage v transposed: cb[f][m']
    {
      const int vr = t & 15, vc0 = (t >> 4) * 8;
      #pragma unroll
      for (int p = 0; p < 8; ++p) {
        const int row = vr + p * 16;
        const int seq = b * S + j * BLK + c * 128 + row;
        const u16x8 vv = *(const u16x8*)&qkv[(size_t)seq * NQKV + h * 384 + 256 + vc0];
        #pragma unroll
        for (int i = 0; i < 8; ++i) cb[vc0 + i][row] = vv[i];
      }
    }
    __syncthreads();
    // PV: acc += P @ vT^T
    #pragma unroll
    for (int kk = 0; kk < 4; ++kk) {
      bf16x8 af[4], bfr[4];
      #pragma unroll
      for (int m = 0; m < 4; ++m)
        af[m] = *(const bf16x8*)&pl[wr * 64 + m * 16 + (lane & 15)][kk * 32 + (lane >> 4) * 8];
      #pragma unroll
      for (int n = 0; n < 4; ++n)
        bfr[n] = *(const bf16x8*)&cb[wc * 64 + n * 16 + (lane & 15)][kk * 32 + (lane >> 4) * 8];
      #pragma unroll
      for (int m = 0; m < 4; ++m)
        #pragma unroll
        for (int n = 0; n < 4; ++n)
          acc[m][n] = __builtin_amdgcn_mfma_f32_16x16x32_bf16(af[m], bfr[n], acc[m][n], 0, 0, 0);
    }
  }

  // epilogue: ob[b][n][h*D + f]
  #pragma unroll
  for (int m = 0; m < 4; ++m)
    #pragma unroll
    for (int n = 0; n < 4; ++n) {
      const int fc = h * D + wc * 64 + n * 16 + (lane & 15);
      #pragma unroll
      for (int r = 0; r < 4; ++r) {
        const int seq = b * S + j * BLK + half * 128 + wr * 64 + m * 16 + ro + r;
        ob[(size_t)seq * HD + fc] = f2bf(acc[m][n][r]);
      }
    }
}

// ---------------- RMSNorm * norm_w * sigmoid-gate -> bf16 ------------------
__global__ __launch_bounds__(256) void norm_gate(
    const unsigned short* __restrict__ ob, const unsigned short* __restrict__ gb,
    const float* __restrict__ nw, unsigned short* __restrict__ og) {
  const int row = blockIdx.x;
  const int t = threadIdx.x;
  const u16x8 ov = *(const u16x8*)&ob[(size_t)row * HD + t * 8];
  float f[8];
  float ss = 0.f;
  #pragma unroll
  for (int i = 0; i < 8; ++i) { f[i] = bf2f(ov[i]); ss += f[i] * f[i]; }
  #pragma unroll
  for (int off = 32; off > 0; off >>= 1) ss += __shfl_down(ss, off, 64);
  __shared__ float red[4];
  if ((t & 63) == 0) red[t >> 6] = ss;
  __syncthreads();
  const float rms = rsqrtf((red[0] + red[1] + red[2] + red[3]) * (1.f / HD) + 1e-6f);
  const u16x8 gv = *(const u16x8*)&gb[(size_t)row * HD + t * 8];
  u16x8 ow;
  #pragma unroll
  for (int i = 0; i < 8; ++i)
    ow[i] = f2bf(f[i] * rms * nw[t * 8 + i] * bf2f(gv[i]));
  *(u16x8*)&og[(size_t)row * HD + t * 8] = ow;
}

extern "C" void kernel_launch(void* const* d_in, const int* in_sizes, int n_in,
                              void* d_out, int out_size, void* d_ws, size_t ws_size,
                              hipStream_t stream) {
  (void)in_sizes; (void)n_in; (void)out_size; (void)ws_size;
  const float* x    = (const float*)d_in[0];
  const float* Wqkv = (const float*)d_in[1];
  const float* Wg   = (const float*)d_in[2];
  const float* Wout = (const float*)d_in[3];
  const float* nw   = (const float*)d_in[4];

  char* ws = (char*)d_ws;
  unsigned short* xb    = (unsigned short*)ws; ws += SZ_XB;
  unsigned short* wqkvt = (unsigned short*)ws; ws += SZ_WQKVT;  // [6144][2048]
  unsigned short* wgt   = (unsigned short*)ws; ws += SZ_WGT;    // [2048][2048] (contiguous after wqkvt)
  unsigned short* woutt = (unsigned short*)ws; ws += SZ_WOUTT;
  unsigned short* qkvb  = (unsigned short*)ws; ws += SZ_QKVB;
  unsigned short* gb    = (unsigned short*)ws; ws += SZ_GB;
  unsigned short* st    = (unsigned short*)ws; ws += SZ_ST;
  unsigned short* ob    = (unsigned short*)ws; ws += SZ_OB;
  unsigned short* og    = xb;  // alias: xb dead after the fused GEMM
  (void)wgt;

  cvt_bf16<<<dim3((NB * S * DIN) / (256 * 8)), 256, 0, stream>>>(x, xb);
  transpose_cvt<<<dim3(NQKV / 32, DIN / 32), 256, 0, stream>>>(Wqkv, wqkvt, DIN, NQKV);
  transpose_cvt<<<dim3(HD / 32, DIN / 32), 256, 0, stream>>>(Wg, wgt, DIN, HD);
  transpose_cvt<<<dim3(HD / 32, HD / 32), 256, 0, stream>>>(Wout, woutt, HD, HD);

  // fused: [qkv | gate] = x @ [Wqkv | Wg]  (Bt rows contiguous: wqkvt+wgt)
  // N = 8192, split at 6144: silu->qkvb, sigmoid->gb
  gemm128<3><<<dim3((NB * S / 128) * ((NQKV + HD) / 128)), 256, 0, stream>>>(
      xb, wqkvt, qkvb, gb, NB * S, NQKV + HD, DIN, NQKV);

  kv_outer<<<dim3(NB * H * NBL), 256, 0, stream>>>(qkvb, st);
  kv_scan<<<dim3((NB * H * D * D) / 256), 256, 0, stream>>>(st);
  attn_mfma<<<dim3(NB * H * NBL * 2), 256, 0, stream>>>(qkvb, st, ob);

  norm_gate<<<dim3(NB * S), 256, 0, stream>>>(ob, gb, nw, og);
  gemm128<0><<<dim3((NB * S / 128) * (HD / 128)), 256, 0, stream>>>(
      og, woutt, d_out, nullptr, NB * S, HD, HD, 0);
}

// Round 7
// 479.207 us; speedup vs baseline: 1.1412x; 1.0936x over previous
//
#include <hip/hip_runtime.h>
#include <cstddef>

typedef float f32x4 __attribute__((ext_vector_type(4)));
typedef __bf16 bf16x8 __attribute__((ext_vector_type(8)));
typedef unsigned short u16x8 __attribute__((ext_vector_type(8)));
typedef unsigned short u16x4 __attribute__((ext_vector_type(4)));

constexpr int NB = 2, S = 4096, H = 16, D = 128;
constexpr int DIN = 2048, NQKV = 6144, HD = 2048;
constexpr int BLK = 256, NBL = 16;

constexpr size_t SZ_XB    = (size_t)NB * S * DIN * 2;
constexpr size_t SZ_WQKVT = (size_t)NQKV * DIN * 2;
constexpr size_t SZ_WGT   = (size_t)HD * DIN * 2;
constexpr size_t SZ_WOUTT = (size_t)HD * HD * 2;
constexpr size_t SZ_QKVB  = (size_t)NB * S * NQKV * 2;
constexpr size_t SZ_GB    = (size_t)NB * S * HD * 2;
constexpr size_t SZ_ST    = (size_t)NB * H * NBL * D * D * 2;
constexpr size_t SZ_OB    = (size_t)NB * S * HD * 2;

__device__ __forceinline__ float bf2f(unsigned short u) {
  return __uint_as_float(((unsigned)u) << 16);
}
__device__ __forceinline__ unsigned short f2bf(float f) {
  unsigned u = __float_as_uint(f);
  u += 0x7fffu + ((u >> 16) & 1u);
  return (unsigned short)(u >> 16);
}
__device__ __forceinline__ void gload16(const void* g, void* l) {
  __builtin_amdgcn_global_load_lds(
      (const __attribute__((address_space(1))) unsigned int*)g,
      (__attribute__((address_space(3))) unsigned int*)l, 16, 0, 0);
}

// ---------------- fp32 -> bf16 elementwise convert (8 elems/thread) --------
__global__ __launch_bounds__(256) void cvt_bf16(
    const float* __restrict__ in, unsigned short* __restrict__ out) {
  const size_t id = (size_t)blockIdx.x * 256 + threadIdx.x;
  const float4 a = *(const float4*)&in[id * 8];
  const float4 c = *(const float4*)&in[id * 8 + 4];
  u16x8 o;
  o[0] = f2bf(a.x); o[1] = f2bf(a.y); o[2] = f2bf(a.z); o[3] = f2bf(a.w);
  o[4] = f2bf(c.x); o[5] = f2bf(c.y); o[6] = f2bf(c.z); o[7] = f2bf(c.w);
  *(u16x8*)&out[id * 8] = o;
}

// ---------------- W[K][N] f32  ->  Wt[N][K] bf16 (32x32 LDS tiles) ---------
__global__ __launch_bounds__(256) void transpose_cvt(
    const float* __restrict__ W, unsigned short* __restrict__ Wt, int K, int N) {
  __shared__ unsigned short tile[32][33];
  const int n0 = blockIdx.x * 32, k0 = blockIdx.y * 32;
  const int t = threadIdx.x;
  const int r = t >> 3, c4 = (t & 7) * 4;
  const float4 v = *(const float4*)&W[(size_t)(k0 + r) * N + n0 + c4];
  tile[r][c4 + 0] = f2bf(v.x);
  tile[r][c4 + 1] = f2bf(v.y);
  tile[r][c4 + 2] = f2bf(v.z);
  tile[r][c4 + 3] = f2bf(v.w);
  __syncthreads();
  u16x4 o;
  #pragma unroll
  for (int i = 0; i < 4; ++i) o[i] = tile[c4 + i][r];
  *(u16x4*)&Wt[(size_t)(n0 + r) * K + k0 + c4] = o;
}

// ---------------- 128^2 m97-structure bf16 MFMA GEMM -----------------------
// A [M][K], Bt [N][K] bf16 row-major. 256 thr = 4 waves (2Mx2N), 64x64/wave.
// BK=64, SINGLE 32 KiB LDS buffer, 2-barrier loop + vmcnt(0) drain; ~3
// blocks/CU co-residency covers the drain stall (m114/m97). Swizzle: 16B
// slot = colgrp ^ (row&7); linear LDS dst t*16, pre-swizzled global source.
// ACT: 0 -> f32 into O1 (stride N); 3 -> fused split: gc<NSPLIT silu->O1
// bf16 (stride NSPLIT), else sigmoid->O2 bf16 (stride N-NSPLIT).
template<int ACT>
__global__ __launch_bounds__(256, 3) void gemm128(
    const unsigned short* __restrict__ A, const unsigned short* __restrict__ Bt,
    void* __restrict__ O1, void* __restrict__ O2,
    int M, int N, int K, int NSPLIT) {
  __shared__ unsigned short lds[16384];          // 32 KiB: A 16K + B 16K
  char* ldsb = (char*)lds;
  const int t = threadIdx.x;
  const int lane = t & 63, wave = t >> 6;
  const int wr = wave >> 1, wc = wave & 1;
  const int l15 = lane & 15;

  const int nbm = M >> 7;
  const int nbmx = nbm >> 3;
  const int xcd = blockIdx.x & 7, q = blockIdx.x >> 3;
  const int bm = xcd * nbmx + (q % nbmx);
  const int bn = q / nbmx;

  const int cg = (t & 7) ^ ((t >> 3) & 7);
  const unsigned short* sA = A  + (size_t)(bm * 128 + (t >> 3)) * K + cg * 8;
  const unsigned short* sB = Bt + (size_t)(bn * 128 + (t >> 3)) * K + cg * 8;
  const int dstb = t << 4;

  int offA[2][4], offB[2][4];
  #pragma unroll
  for (int kk = 0; kk < 2; ++kk) {
    #pragma unroll
    for (int m = 0; m < 4; ++m) {
      const int row = wr * 64 + m * 16 + l15;
      offA[kk][m] = row * 128 + (((kk * 4 + (lane >> 4)) ^ (row & 7)) << 4);
    }
    #pragma unroll
    for (int n = 0; n < 4; ++n) {
      const int row = wc * 64 + n * 16 + l15;
      offB[kk][n] = 16384 + row * 128 + (((kk * 4 + (lane >> 4)) ^ (row & 7)) << 4);
    }
  }

  const int NT = K >> 6;
  f32x4 acc[4][4] = {};
  for (int u = 0; u < NT; ++u) {
    __syncthreads();
    const int ko = u * 64;
    #pragma unroll
    for (int i = 0; i < 4; ++i) {
      gload16(sA + (size_t)(i * 32) * K + ko, ldsb + i * 4096 + dstb);
      gload16(sB + (size_t)(i * 32) * K + ko, ldsb + 16384 + i * 4096 + dstb);
    }
    asm volatile("s_waitcnt vmcnt(0)" ::: "memory");
    __syncthreads();
    #pragma unroll
    for (int kk = 0; kk < 2; ++kk) {
      bf16x8 af[4], bfr[4];
      #pragma unroll
      for (int m = 0; m < 4; ++m) af[m] = *(const bf16x8*)(ldsb + offA[kk][m]);
      #pragma unroll
      for (int n = 0; n < 4; ++n) bfr[n] = *(const bf16x8*)(ldsb + offB[kk][n]);
      #pragma unroll
      for (int m = 0; m < 4; ++m)
        #pragma unroll
        for (int n = 0; n < 4; ++n)
          acc[m][n] = __builtin_amdgcn_mfma_f32_16x16x32_bf16(af[m], bfr[n], acc[m][n], 0, 0, 0);
    }
  }

  // epilogue: C/D layout col = lane&15, row = (lane>>4)*4 + reg  [m89-verified]
  const int ro = (lane >> 4) * 4, co = l15;
  const bool lo = (bn * 128) < NSPLIT;
  #pragma unroll
  for (int m = 0; m < 4; ++m)
    #pragma unroll
    for (int n = 0; n < 4; ++n) {
      const int gc = bn * 128 + wc * 64 + n * 16 + co;
      #pragma unroll
      for (int r = 0; r < 4; ++r) {
        const int gr = bm * 128 + wr * 64 + m * 16 + ro + r;
        float v = acc[m][n][r];
        if constexpr (ACT == 0) {
          ((float*)O1)[(size_t)gr * N + gc] = v;
        } else {
          if (lo) {
            v = v / (1.f + __expf(-v));          // silu
            ((unsigned short*)O1)[(size_t)gr * NSPLIT + gc] = f2bf(v);
          } else {
            v = 1.f / (1.f + __expf(-v));        // sigmoid
            ((unsigned short*)O2)[(size_t)gr * (N - NSPLIT) + (gc - NSPLIT)] = f2bf(v);
          }
        }
      }
    }
}

// ---------------- per-block KV outer product (MFMA), TRANSPOSED out --------
// st[(bh*NBL+j)][f][e] = sum_m (k[m][e]*kdecay[m]) * v[m][f]   (bf16)
// 4 waves 2x2 (wave 64x64 out), m chunked by 64 (K=256 total), operands
// staged TRANSPOSED ([dim][m], 144B rows -> bank-spread, 16B aligned).
__global__ __launch_bounds__(256) void kv_outer(
    const unsigned short* __restrict__ qkv, unsigned short* __restrict__ st) {
  const int gid = blockIdx.x;
  const int j = gid & 15;
  const int bh = gid >> 4;
  const int h = bh & 15;
  const int b = bh >> 4;
  const float slope = exp2f(-0.5f * (float)(h + 1));
  const int t = threadIdx.x;
  const int lane = t & 63, wave = t >> 6, wr = wave >> 1, wc = wave & 1;
  const int l15 = lane & 15;
  __shared__ unsigned short vt[128][72];   // vT [f][mm]
  __shared__ unsigned short kt[128][72];   // (k*kd)T [e][mm]
  f32x4 acc[4][4] = {};
  const int mm = t & 63;                   // m within chunk
  const int c0 = (t >> 6) * 32;            // 32-col span per wave
  for (int ch = 0; ch < 4; ++ch) {
    if (ch) __syncthreads();
    const int m = ch * 64 + mm;
    const int seq = b * S + j * BLK + m;
    const float kd = expf(-slope * (float)(255 - m));
    const unsigned short* row = &qkv[(size_t)seq * NQKV + h * 384];
    #pragma unroll
    for (int i = 0; i < 4; ++i) {
      const u16x8 k8 = *(const u16x8*)&row[128 + c0 + i * 8];
      const u16x8 v8 = *(const u16x8*)&row[256 + c0 + i * 8];
      #pragma unroll
      for (int q2 = 0; q2 < 8; ++q2) {
        kt[c0 + i * 8 + q2][mm] = f2bf(bf2f(k8[q2]) * kd);
        vt[c0 + i * 8 + q2][mm] = v8[q2];
      }
    }
    __syncthreads();
    #pragma unroll
    for (int kk = 0; kk < 2; ++kk) {
      bf16x8 af[4], bfr[4];
      #pragma unroll
      for (int mi = 0; mi < 4; ++mi)
        af[mi] = *(const bf16x8*)&vt[wr * 64 + mi * 16 + l15][kk * 32 + (lane >> 4) * 8];
      #pragma unroll
      for (int n = 0; n < 4; ++n)
        bfr[n] = *(const bf16x8*)&kt[wc * 64 + n * 16 + l15][kk * 32 + (lane >> 4) * 8];
      #pragma unroll
      for (int mi = 0; mi < 4; ++mi)
        #pragma unroll
        for (int n = 0; n < 4; ++n)
          acc[mi][n] = __builtin_amdgcn_mfma_f32_16x16x32_bf16(af[mi], bfr[n], acc[mi][n], 0, 0, 0);
    }
  }
  // epilogue: D[f][e], f = wr*64+mi*16+(lane>>4)*4+r, e = wc*64+n*16+l15
  const size_t base = (size_t)gid * (D * D);
  const int ro = (lane >> 4) * 4;
  #pragma unroll
  for (int mi = 0; mi < 4; ++mi)
    #pragma unroll
    for (int n = 0; n < 4; ++n) {
      const int e = wc * 64 + n * 16 + l15;
      #pragma unroll
      for (int r = 0; r < 4; ++r) {
        const int f = wr * 64 + mi * 16 + ro + r;
        st[base + (size_t)f * D + e] = f2bf(acc[mi][n][r]);
      }
    }
}

// ---------------- exclusive decay scan over blocks (per element) -----------
__global__ __launch_bounds__(256) void kv_scan(unsigned short* __restrict__ st) {
  const int id = blockIdx.x * 256 + threadIdx.x;  // NB*H*D*D threads
  const int ef = id & (D * D - 1);
  const int bh = id >> 14;
  const int h = bh & 15;
  const float slope = exp2f(-0.5f * (float)(h + 1));
  const float bd = expf(-slope * 256.f);
  unsigned short* p = st + (size_t)bh * NBL * D * D + ef;
  float cur = 0.f;
  #pragma unroll
  for (int jj = 0; jj < NBL; ++jj) {
    const float m = bf2f(p[(size_t)jj * D * D]);
    p[(size_t)jj * D * D] = f2bf(cur);
    cur = bd * cur + m;
  }
}

// ---------------- MFMA attention (q in registers, 2 blocks/CU) -------------
// grid = ((b*H+h)*NBL + j)*2 + half ; WG = 4 waves, 128 q-rows x 128 dims.
// out = qdecay.*(q @ kvT^T) + (mask(q@k^T).*decay) @ v
__global__ __launch_bounds__(256, 2) void attn_mfma(
    const unsigned short* __restrict__ qkv, const unsigned short* __restrict__ st,
    unsigned short* __restrict__ ob) {
  const int gid = blockIdx.x;
  const int half = gid & 1;
  const int rest = gid >> 1;
  const int j = rest & 15;
  const int bh = rest >> 4;
  const int h = bh & 15;
  const int b = bh >> 4;
  const float slope = exp2f(-0.5f * (float)(h + 1));
  const int t = threadIdx.x;
  const int lane = t & 63, wave = t >> 6, wr = wave >> 1, wc = wave & 1;

  __shared__ unsigned short cb[128][136];   // kvT / k / vT chunk buffer
  __shared__ unsigned short pl[128][136];   // decayed P (m x m') bf16

  // q fragments direct from global (L2-resident; frag layout = MFMA A-frag)
  bf16x8 af[4][4];                          // [kk][m]
  #pragma unroll
  for (int m = 0; m < 4; ++m) {
    const int seq = b * S + j * BLK + half * 128 + wr * 64 + m * 16 + (lane & 15);
    const unsigned short* qrow = &qkv[(size_t)seq * NQKV + h * 384];
    #pragma unroll
    for (int kk = 0; kk < 4; ++kk)
      af[kk][m] = *(const bf16x8*)&qrow[kk * 32 + (lane >> 4) * 8];
  }
  // stage kvT (state pre-transposed [f][e], exclusive-scanned)
  {
    const int r = t >> 4, c0 = (t & 15) * 8;
    const size_t stbase = (size_t)rest * (D * D);
    #pragma unroll
    for (int p = 0; p < 8; ++p)
      *(u16x8*)&cb[r + p * 16][c0] = *(const u16x8*)&st[stbase + (size_t)(r + p * 16) * D + c0];
  }
  __syncthreads();

  f32x4 acc[4][4] = {};
  // ---- phase 1: non-diag = q @ kvT^T ----
  #pragma unroll
  for (int kk = 0; kk < 4; ++kk) {
    bf16x8 bfr[4];
    #pragma unroll
    for (int n = 0; n < 4; ++n)
      bfr[n] = *(const bf16x8*)&cb[wc * 64 + n * 16 + (lane & 15)][kk * 32 + (lane >> 4) * 8];
    #pragma unroll
    for (int m = 0; m < 4; ++m)
      #pragma unroll
      for (int n = 0; n < 4; ++n)
        acc[m][n] = __builtin_amdgcn_mfma_f32_16x16x32_bf16(af[kk][m], bfr[n], acc[m][n], 0, 0, 0);
  }
  // apply q_decay = exp(-slope*(gm+1))
  const int ro = (lane >> 4) * 4;
  #pragma unroll
  for (int m = 0; m < 4; ++m)
    #pragma unroll
    for (int r = 0; r < 4; ++r) {
      const int gm = half * 128 + wr * 64 + m * 16 + ro + r;
      const float qd = expf(-slope * (float)(gm + 1));
      #pragma unroll
      for (int n = 0; n < 4; ++n) acc[m][n][r] *= qd;
    }

  // ---- phase 2: intra-block causal, chunks of 128 k-rows ----
  const int nch = 1 + half;
  for (int c = 0; c < nch; ++c) {
    __syncthreads();                         // cb readers retired
    {
      const int r = t >> 4, c0 = (t & 15) * 8;
      #pragma unroll
      for (int p = 0; p < 8; ++p) {
        const int seq = b * S + j * BLK + c * 128 + r + p * 16;
        *(u16x8*)&cb[r + p * 16][c0] = *(const u16x8*)&qkv[(size_t)seq * NQKV + h * 384 + 128 + c0];
      }
    }
    __syncthreads();
    f32x4 sacc[4][4] = {};
    #pragma unroll
    for (int kk = 0; kk < 4; ++kk) {
      bf16x8 bfr[4];
      #pragma unroll
      for (int n = 0; n < 4; ++n)
        bfr[n] = *(const bf16x8*)&cb[wc * 64 + n * 16 + (lane & 15)][kk * 32 + (lane >> 4) * 8];
      #pragma unroll
      for (int m = 0; m < 4; ++m)
        #pragma unroll
        for (int n = 0; n < 4; ++n)
          sacc[m][n] = __builtin_amdgcn_mfma_f32_16x16x32_bf16(af[kk][m], bfr[n], sacc[m][n], 0, 0, 0);
    }
    // decay+mask -> P (bf16) in LDS
    #pragma unroll
    for (int m = 0; m < 4; ++m)
      #pragma unroll
      for (int n = 0; n < 4; ++n) {
        const int lc = wc * 64 + n * 16 + (lane & 15);
        const int gp = c * 128 + lc;
        #pragma unroll
        for (int r = 0; r < 4; ++r) {
          const int lm = wr * 64 + m * 16 + ro + r;
          const int gm = half * 128 + lm;
          const float dd = (gm >= gp) ? expf(-slope * (float)(gm - gp)) : 0.f;
          pl[lm][lc] = f2bf(sacc[m][n][r] * dd);
        }
      }
    __syncthreads();                         // P complete; cb(k) readers done
    // stage v transposed: cb[f][m']
    {
      const int vr = t & 15, vc0 = (t >> 4) * 8;
      #pragma unroll
      for (int p = 0; p < 8; ++p) {
        const int row = vr + p * 16;
        const int seq = b * S + j * BLK + c * 128 + row;
        const u16x8 vv = *(const u16x8*)&qkv[(size_t)seq * NQKV + h * 384 + 256 + vc0];
        #pragma unroll
        for (int i = 0; i < 8; ++i) cb[vc0 + i][row] = vv[i];
      }
    }
    __syncthreads();
    // PV: acc += P @ vT^T
    #pragma unroll
    for (int kk = 0; kk < 4; ++kk) {
      bf16x8 pf[4], bfr[4];
      #pragma unroll
      for (int m = 0; m < 4; ++m)
        pf[m] = *(const bf16x8*)&pl[wr * 64 + m * 16 + (lane & 15)][kk * 32 + (lane >> 4) * 8];
      #pragma unroll
      for (int n = 0; n < 4; ++n)
        bfr[n] = *(const bf16x8*)&cb[wc * 64 + n * 16 + (lane & 15)][kk * 32 + (lane >> 4) * 8];
      #pragma unroll
      for (int m = 0; m < 4; ++m)
        #pragma unroll
        for (int n = 0; n < 4; ++n)
          acc[m][n] = __builtin_amdgcn_mfma_f32_16x16x32_bf16(pf[m], bfr[n], acc[m][n], 0, 0, 0);
    }
  }

  // epilogue: ob[b][n][h*D + f]
  #pragma unroll
  for (int m = 0; m < 4; ++m)
    #pragma unroll
    for (int n = 0; n < 4; ++n) {
      const int fc = h * D + wc * 64 + n * 16 + (lane & 15);
      #pragma unroll
      for (int r = 0; r < 4; ++r) {
        const int seq = b * S + j * BLK + half * 128 + wr * 64 + m * 16 + ro + r;
        ob[(size_t)seq * HD + fc] = f2bf(acc[m][n][r]);
      }
    }
}

// ---------------- RMSNorm * norm_w * sigmoid-gate -> bf16 ------------------
__global__ __launch_bounds__(256) void norm_gate(
    const unsigned short* __restrict__ ob, const unsigned short* __restrict__ gb,
    const float* __restrict__ nw, unsigned short* __restrict__ og) {
  const int row = blockIdx.x;
  const int t = threadIdx.x;
  const u16x8 ov = *(const u16x8*)&ob[(size_t)row * HD + t * 8];
  float f[8];
  float ss = 0.f;
  #pragma unroll
  for (int i = 0; i < 8; ++i) { f[i] = bf2f(ov[i]); ss += f[i] * f[i]; }
  #pragma unroll
  for (int off = 32; off > 0; off >>= 1) ss += __shfl_down(ss, off, 64);
  __shared__ float red[4];
  if ((t & 63) == 0) red[t >> 6] = ss;
  __syncthreads();
  const float rms = rsqrtf((red[0] + red[1] + red[2] + red[3]) * (1.f / HD) + 1e-6f);
  const u16x8 gv = *(const u16x8*)&gb[(size_t)row * HD + t * 8];
  u16x8 ow;
  #pragma unroll
  for (int i = 0; i < 8; ++i)
    ow[i] = f2bf(f[i] * rms * nw[t * 8 + i] * bf2f(gv[i]));
  *(u16x8*)&og[(size_t)row * HD + t * 8] = ow;
}

extern "C" void kernel_launch(void* const* d_in, const int* in_sizes, int n_in,
                              void* d_out, int out_size, void* d_ws, size_t ws_size,
                              hipStream_t stream) {
  (void)in_sizes; (void)n_in; (void)out_size; (void)ws_size;
  const float* x    = (const float*)d_in[0];
  const float* Wqkv = (const float*)d_in[1];
  const float* Wg   = (const float*)d_in[2];
  const float* Wout = (const float*)d_in[3];
  const float* nw   = (const float*)d_in[4];

  char* ws = (char*)d_ws;
  unsigned short* xb    = (unsigned short*)ws; ws += SZ_XB;
  unsigned short* wqkvt = (unsigned short*)ws; ws += SZ_WQKVT;  // [6144][2048]
  unsigned short* wgt   = (unsigned short*)ws; ws += SZ_WGT;    // [2048][2048] (contiguous after wqkvt)
  unsigned short* woutt = (unsigned short*)ws; ws += SZ_WOUTT;
  unsigned short* qkvb  = (unsigned short*)ws; ws += SZ_QKVB;
  unsigned short* gb    = (unsigned short*)ws; ws += SZ_GB;
  unsigned short* st    = (unsigned short*)ws; ws += SZ_ST;
  unsigned short* ob    = (unsigned short*)ws; ws += SZ_OB;
  unsigned short* og    = xb;  // alias: xb dead after the fused GEMM
  (void)wgt;

  cvt_bf16<<<dim3((NB * S * DIN) / (256 * 8)), 256, 0, stream>>>(x, xb);
  transpose_cvt<<<dim3(NQKV / 32, DIN / 32), 256, 0, stream>>>(Wqkv, wqkvt, DIN, NQKV);
  transpose_cvt<<<dim3(HD / 32, DIN / 32), 256, 0, stream>>>(Wg, wgt, DIN, HD);
  transpose_cvt<<<dim3(HD / 32, HD / 32), 256, 0, stream>>>(Wout, woutt, HD, HD);

  // fused: [qkv | gate] = x @ [Wqkv | Wg]; N = 8192, split at 6144
  gemm128<3><<<dim3((NB * S / 128) * ((NQKV + HD) / 128)), 256, 0, stream>>>(
      xb, wqkvt, qkvb, gb, NB * S, NQKV + HD, DIN, NQKV);

  kv_outer<<<dim3(NB * H * NBL), 256, 0, stream>>>(qkvb, st);
  kv_scan<<<dim3((NB * H * D * D) / 256), 256, 0, stream>>>(st);
  attn_mfma<<<dim3(NB * H * NBL * 2), 256, 0, stream>>>(qkvb, st, ob);

  norm_gate<<<dim3(NB * S), 256, 0, stream>>>(ob, gb, nw, og);
  gemm128<0><<<dim3((NB * S / 128) * (HD / 128)), 256, 0, stream>>>(
      og, woutt, d_out, nullptr, NB * S, HD, HD, 0);
}